// Round 3
// baseline (363.221 us; speedup 1.0000x reference)
//
#include <hip/hip_runtime.h>
#include <hip/hip_bf16.h>
#include <math.h>

#define BB 2
#define TT 2048
#define CC 2048
#define NH 16
#define NKV 4
#define HD 128
#define BT (BB*TT)
#define WINDOW 1024
#define SQKV 3072   // QKV buffer row stride: Q cols 0-2047, K 2048-2559, V 2560-3071

typedef unsigned short u16;
typedef unsigned int u32;
typedef __attribute__((ext_vector_type(8))) short short8;      // 8 bf16 = 4 VGPRs (MFMA A/B frag)
typedef __attribute__((ext_vector_type(8))) unsigned short ushort8;
typedef __attribute__((ext_vector_type(4))) unsigned short ushort4v;
typedef __attribute__((ext_vector_type(2))) unsigned int uint2v;
typedef __attribute__((ext_vector_type(4))) float floatx4;     // 16x16 MFMA C/D frag
typedef __attribute__((ext_vector_type(16))) float floatx16;   // 32x32 MFMA C/D frag

typedef const __attribute__((address_space(1))) u32* gas_ptr;
typedef __attribute__((address_space(3))) u32* las_ptr;

static __device__ __forceinline__ u16 f2bf(float f) {
    unsigned u = __builtin_bit_cast(unsigned, f);
    return (u16)((u + 0x7fffu + ((u >> 16) & 1u)) >> 16);   // RNE
}
static __device__ __forceinline__ float bf2f(u16 v) {
    unsigned u = ((unsigned)v) << 16;
    return __builtin_bit_cast(float, u);
}

// packed f32x2 -> bf16x2 (RNE), low half = lo, high half = hi
static __device__ __forceinline__ u32 cvt_pk_bf16(float lo, float hi) {
    u32 r;
    asm("v_cvt_pk_bf16_f32 %0, %1, %2" : "=v"(r) : "v"(lo), "v"(hi));
    return r;
}

// softcap+exp: exp(50*tanh(s/50)) = exp2( t*(c0 + c1 t^2 + c2 t^4) ), t=s/50 clamped to [-1,1].
static __device__ __forceinline__ float softcap_exp(float s) {
    float t = s * 0.02f;
    t = fmaxf(-1.0f, fminf(1.0f, t));     // v_med3
    float t2 = t * t;
    float e = t * fmaf(t2, fmaf(t2, 9.617967f, -24.044917f), 72.134752f);
    return __builtin_amdgcn_exp2f(e);
}

// ---------------- elementwise cast fp32 -> bf16 ----------------
__global__ void cast_bf16_kernel(const float* __restrict__ in, u16* __restrict__ out, int n4) {
    int i = blockIdx.x * blockDim.x + threadIdx.x;
    if (i >= n4) return;
    floatx4 v = *(const floatx4*)(in + (size_t)i * 4);
    ushort4v o;
    o[0] = f2bf(v[0]); o[1] = f2bf(v[1]); o[2] = f2bf(v[2]); o[3] = f2bf(v[3]);
    *(ushort4v*)(out + (size_t)i * 4) = o;
}

// ---------------- transpose + cast fp32 [R][Cc] -> bf16 [Cc][R] ----------------
__global__ void transpose_cast_f32_kernel(const float* __restrict__ in, u16* __restrict__ out,
                                          int R, int Cc) {
    __shared__ u16 tile[32][33];
    int c0 = blockIdx.x * 32, r0 = blockIdx.y * 32;
    int tx = threadIdx.x, ty = threadIdx.y;   // block (32, 8)
    #pragma unroll
    for (int i = 0; i < 4; i++) {
        int r = r0 + ty + i * 8;
        tile[ty + i * 8][tx] = f2bf(in[(size_t)r * Cc + c0 + tx]);
    }
    __syncthreads();
    #pragma unroll
    for (int i = 0; i < 4; i++) {
        int c = c0 + ty + i * 8;
        out[(size_t)c * R + r0 + tx] = tile[tx][ty + i * 8];
    }
}

// ---------------- strided transpose bf16: in[r][colOff + c] -> out [Cc][R], batched z ----------------
__global__ void transpose_bf16_kernel(const u16* __restrict__ in, u16* __restrict__ out,
                                      int R, int Cc, int inStride, int colOff,
                                      size_t inBatchStride, size_t outBatchStride) {
    __shared__ u16 tile[32][33];
    int b = blockIdx.z;
    const u16* inb = in + (size_t)b * inBatchStride;
    u16* outb = out + (size_t)b * outBatchStride;
    int c0 = blockIdx.y * 32, r0 = blockIdx.x * 32;
    int tx = threadIdx.x, ty = threadIdx.y;   // block (32, 8)
    #pragma unroll
    for (int i = 0; i < 4; i++) {
        int r = r0 + ty + i * 8;
        tile[ty + i * 8][tx] = inb[(size_t)r * inStride + colOff + c0 + tx];
    }
    __syncthreads();
    #pragma unroll
    for (int i = 0; i < 4; i++) {
        int c = c0 + ty + i * 8;
        outb[(size_t)c * R + r0 + tx] = tile[tx][ty + i * 8];
    }
}

// ---------------- RoPE in-place on rows of `rowStride` elems, H heads x 128, fold scale ----------------
__global__ void rope_kernel(u16* __restrict__ buf, int H, int rowStride, float scale) {
    int idx = blockIdx.x;                 // bt*H + h
    int bt = idx / H, h = idx - bt * H;
    int t = bt % TT;
    int d = threadIdx.x;                  // 0..127
    u16* p = buf + (size_t)bt * rowStride + h * HD;
    float x  = bf2f(p[d]);
    float xp = bf2f(p[d ^ 64]);
    int j = d & 63;
    float inv = exp2f(-0.20762050593046f * (float)j);   // 10000^(-j/64)
    float ang = (float)t * inv;
    float s, c;
    sincosf(ang, &s, &c);
    float rot = (d < 64) ? -xp : xp;
    float o = (x * c + rot * s) * scale;
    __syncthreads();                      // all reads done before any write
    p[d] = f2bf(o);
}

// ---------------- GEMM v2: 128x128 tile, 8 waves, BK=64, counted vmcnt, frag-major LDS ----------------
// C[M][N] = A[M][K] * Bt[N][K]^T (bf16 in, fp32 acc).
// 512 threads = 8 waves (2M x 4N); per-wave C = 64x32 = 4m x 2n fragments of 16x16.
// LDS: 2 buffers x 32KB. Each buffer is FRAG-MAJOR: 32 groups of 1KB, one per MFMA fragment
// (A: groups (mf*2+ksub), mf in [0,8); B: +16KB, (nf*2+ksub)). Group content: lane l holds
// matrix[row = mf*16 + (l&15)][k = ksub*32 + (l>>4)*8 .. +8] -- exactly the MFMA A/B frag layout.
// => every ds_read_b128 is lane-consecutive 16B: ZERO bank conflicts by construction.
// Achieved by pre-permuting the per-lane GLOBAL source of each global_load_lds (linear LDS dest).
// Pipeline: stage(t+2) issues right after the barrier that frees buf[t&1]; wait is vmcnt(4)
// (next tile's 4 loads stay IN FLIGHT across the barrier -- never drain to 0 in the loop).
template <bool OUT_F32>
__global__ __launch_bounds__(512, 4) void gemm128x8_kernel(const u16* __restrict__ A,
                                                           const u16* __restrict__ Bt,
                                                           void* __restrict__ Cout,
                                                           int M, int N, int K) {
    __shared__ alignas(16) u16 lds[2 * 16384];   // 2 x 32KB
    int tid = threadIdx.x;
    int w = tid >> 6, lane = tid & 63, quad = lane >> 4, ln = lane & 15;
    int wm = w >> 2, wn = w & 3;                 // wave tile: rows wm*64, cols wn*32
    int m0 = blockIdx.y * 128;
    int n0 = blockIdx.x * 128;

    // staging: thread covers groups g = j*8 + w (j=0..3); g<16: A-frag groups, g>=16: B-frag groups
    const u16* gsrc[4];
    #pragma unroll
    for (int j = 0; j < 4; j++) {
        int g = j * 8 + w;
        int gl = g & 15;
        int mf = gl >> 1, ks = gl & 1;
        const u16* base = (g < 16) ? (A + (size_t)m0 * K) : (Bt + (size_t)n0 * K);
        gsrc[j] = base + (size_t)(mf * 16 + ln) * K + ks * 32 + quad * 8;
    }
    int ldst = w * 512 + lane * 8;               // u16 offset within a j-section (4096 u16 per j)

    floatx4 acc[4][2] = {};
    int nk = K >> 6;

    auto stage = [&](int t) {
        u16* dst = lds + (t & 1) * 16384;
        int k0 = t * 64;
        #pragma unroll
        for (int j = 0; j < 4; j++)
            __builtin_amdgcn_global_load_lds((gas_ptr)(gsrc[j] + k0),
                                             (las_ptr)(dst + j * 4096 + ldst), 16, 0, 0);
    };

    stage(0);
    stage(1);
    __builtin_amdgcn_s_waitcnt(0x0F74);          // vmcnt(4): tile-0 loads landed, tile-1 in flight
    __builtin_amdgcn_sched_barrier(0);
    __builtin_amdgcn_s_barrier();                // all waves' tile-0 loads visible
    __builtin_amdgcn_sched_barrier(0);

    for (int t = 0; t < nk; ++t) {
        const u16* buf = lds + (t & 1) * 16384;

        short8 bfr[2][2];
        #pragma unroll
        for (int n = 0; n < 2; n++)
            #pragma unroll
            for (int ks = 0; ks < 2; ks++)
                bfr[n][ks] = *(const short8*)(buf + 8192 + ((wn * 2 + n) * 2 + ks) * 512 + lane * 8);

        __builtin_amdgcn_s_setprio(1);
        #pragma unroll
        for (int m = 0; m < 4; m++) {
            short8 af0 = *(const short8*)(buf + ((wm * 4 + m) * 2 + 0) * 512 + lane * 8);
            short8 af1 = *(const short8*)(buf + ((wm * 4 + m) * 2 + 1) * 512 + lane * 8);
            #pragma unroll
            for (int n = 0; n < 2; n++) {
                acc[m][n] = __builtin_amdgcn_mfma_f32_16x16x32_bf16(af0, bfr[n][0], acc[m][n], 0, 0, 0);
                acc[m][n] = __builtin_amdgcn_mfma_f32_16x16x32_bf16(af1, bfr[n][1], acc[m][n], 0, 0, 0);
            }
        }
        __builtin_amdgcn_s_setprio(0);

        __builtin_amdgcn_sched_barrier(0);
        __builtin_amdgcn_s_barrier();            // all waves done reading buf[t&1]
        __builtin_amdgcn_sched_barrier(0);

        if (t + 2 < nk) {
            stage(t + 2);                         // into buf[t&1] (just freed)
            __builtin_amdgcn_sched_barrier(0);
            __builtin_amdgcn_s_waitcnt(0x0F74);  // vmcnt(4): tile t+1 landed, t+2 in flight
            __builtin_amdgcn_sched_barrier(0);
            __builtin_amdgcn_s_barrier();        // all waves' t+1 loads visible
            __builtin_amdgcn_sched_barrier(0);
        } else if (t + 1 < nk) {
            __builtin_amdgcn_s_waitcnt(0x0F70);  // vmcnt(0): last tile, drain
            __builtin_amdgcn_sched_barrier(0);
            __builtin_amdgcn_s_barrier();
            __builtin_amdgcn_sched_barrier(0);
        }
    }

    #pragma unroll
    for (int m = 0; m < 4; m++)
      #pragma unroll
      for (int n = 0; n < 2; n++)
        #pragma unroll
        for (int r = 0; r < 4; r++) {
            size_t row = m0 + wm * 64 + m * 16 + quad * 4 + r;
            size_t col = n0 + wn * 32 + n * 16 + ln;
            float v = acc[m][n][r];
            if (OUT_F32) ((float*)Cout)[row * N + col] = v;
            else         ((u16*)Cout)[row * N + col] = f2bf(v);
        }
}

// ---------------- flash attention v3: shared K/V tiles, 128-query blocks ----------------
// Block = 128 queries x (b,h), 4 waves each owning 32 queries. All waves iterate the SAME key
// tiles; K/V staged in LDS once per block via global_load_lds (16 x 1KB DMA, 4 per wave),
// double-buffered with one-tile-ahead prefetch. Raw s_barrier + counted vmcnt(4).
// LDS layout = read order: every ds_read_b128 is lane-linear over a contiguous 1KB group =>
// conflict-free. In-register softmax via sigma-permuted K rows + cvt_pk P-pack:
//   sigma(m) = (m&3) + 4*bit3(m) + 8*bit2(m) + 16*bit4(m)
//   S^T reg r holds key s0 + (r&3) + 4*((r>>2)&1) + 8*hi + 16*(r>>3), col q = ln.
__global__ __launch_bounds__(256, 2) void attn_kernel(const u16* __restrict__ QKV,
                                                      const u16* __restrict__ Vt,
                                                      u16* __restrict__ Enc) {
    // buf[2] x { K: 8KB (groups ks=0..7, 1KB each) | V: 8KB (groups g=dt*2+half) } = 32KB
    __shared__ alignas(16) u16 pool[2 * 8192];

    int tid = threadIdx.x;
    int w = tid >> 6, lane = tid & 63, hi = lane >> 5, ln = lane & 31;
    int hi8 = hi * 8;

    int qb = (15 - (int)blockIdx.x) * 128;      // long blocks first
    int bh = blockIdx.y;
    int b = bh >> 4, h = bh & 15, kh = h >> 2;
    int qw = qb + w * 32;                        // this wave's query base

    // Q B-frag [n=q=ln][k=hi*8 + ks*16 + j]
    short8 qf[8];
    {
        const u16* qptr = QKV + (size_t)(b * TT + qw + ln) * SQKV + h * HD + hi8;
        #pragma unroll
        for (int ks = 0; ks < 8; ks++) qf[ks] = *(const short8*)(qptr + ks * 16);
    }

    // ---- DMA source setup: wave w issues groups [w*4, w*4+4) of {K0..7, V0..7} ----
    int sig = (ln & 3) + (((ln >> 3) & 1) << 2) + (((ln >> 2) & 1) << 3) + ((ln >> 4) << 4);
    bool isK = (w < 2);
    const u16* dsrc[4];
    int ldst[4];                                 // u16 offset within a 16KB buffer
    #pragma unroll
    for (int i = 0; i < 4; i++) {
        if (isK) {
            int ks = w * 4 + i;
            dsrc[i] = QKV + (size_t)(b * TT + sig) * SQKV + 2048 + kh * HD + ks * 16 + hi8;
            ldst[i] = ks * 512;
        } else {
            int g = (w - 2) * 4 + i;
            dsrc[i] = Vt + (size_t)((b * NKV + kh) * HD + (g >> 1) * 32 + ln) * TT + (g & 1) * 16 + hi8;
            ldst[i] = 4096 + g * 512;
        }
    }
    size_t addmul = isK ? (size_t)SQKV : (size_t)1;

    floatx16 O0 = {}, O1 = {}, O2 = {}, O3 = {};   // O^T d-tiles: D[m=d][n=q]
    float lacc = 0.0f;

    int S_LO = qb - WINDOW; if (S_LO < 0) S_LO = 0;
    int nt = (qb + 128 - S_LO) >> 5;

    auto issue = [&](int t) {
        int s0 = S_LO + t * 32;
        u16* base = pool + (t & 1) * 8192;
        size_t add = (size_t)s0 * addmul;
        #pragma unroll
        for (int i = 0; i < 4; i++)
            __builtin_amdgcn_global_load_lds((gas_ptr)(dsrc[i] + add), (las_ptr)(base + ldst[i]), 16, 0, 0);
    };

    issue(0);
    for (int t = 0; t < nt; ++t) {
        // barrier A: all waves done reading buf[(t+1)&1] (= tile t-1's buffer)
        __builtin_amdgcn_sched_barrier(0);
        __builtin_amdgcn_s_barrier();
        __builtin_amdgcn_sched_barrier(0);
        if (t + 1 < nt) {
            issue(t + 1);
            __builtin_amdgcn_sched_barrier(0);
            __builtin_amdgcn_s_waitcnt(0x0F74);   // vmcnt(4): own tile-t DMAs landed, t+1 in flight
        } else {
            __builtin_amdgcn_s_waitcnt(0x0F70);   // vmcnt(0): last tile, drain all
        }
        __builtin_amdgcn_sched_barrier(0);
        __builtin_amdgcn_s_barrier();             // barrier B: ALL waves' tile-t data in LDS
        __builtin_amdgcn_sched_barrier(0);

        int s0 = S_LO + t * 32;
        if (s0 > qw + 31 || s0 + 31 < qw - WINDOW) continue;   // tile outside this wave's window

        const u16* Kb = pool + (t & 1) * 8192;
        const u16* Vb = Kb + 4096;

        // ---- S^T = K Q^T (rows = sigma-permuted keys, cols = q) ----
        floatx16 S = {};
        #pragma unroll
        for (int ks = 0; ks < 8; ks++) {
            short8 kf = *(const short8*)(Kb + ks * 512 + lane * 8);   // lane-linear: conflict-free
            S = __builtin_amdgcn_mfma_f32_32x32x16_bf16(kf, qf[ks], S, 0, 0, 0);
        }

        // ---- softcap + exp (+ mask only on edge tiles), in place ----
        bool full = (s0 + 31 <= qw) && (s0 >= qw + 31 - WINDOW);
        if (full) {
            #pragma unroll
            for (int r = 0; r < 16; r++) S[r] = softcap_exp(S[r]);
        } else {
            int tq = qw + ln;
            #pragma unroll
            for (int r = 0; r < 16; r++) {
                int s = s0 + (r & 3) + (((r >> 2) & 1) << 2) + hi8 + ((r >> 3) << 4);
                bool good = (s <= tq) && (s >= tq - WINDOW);
                S[r] = good ? softcap_exp(S[r]) : 0.0f;
            }
        }

        // ---- own-half l accumulation (tree) ----
        lacc += ((((S[0] + S[1]) + (S[2] + S[3])) + ((S[4] + S[5]) + (S[6] + S[7])))
               + (((S[8] + S[9]) + (S[10] + S[11])) + ((S[12] + S[13]) + (S[14] + S[15]))));

        // ---- pack P -> bf16 B-frags (already frag-ordered thanks to sigma) ----
        u32 w0a = cvt_pk_bf16(S[0],  S[1]),  w0b = cvt_pk_bf16(S[2],  S[3]);
        u32 w0c = cvt_pk_bf16(S[4],  S[5]),  w0d = cvt_pk_bf16(S[6],  S[7]);
        u32 w1a = cvt_pk_bf16(S[8],  S[9]),  w1b = cvt_pk_bf16(S[10], S[11]);
        u32 w1c = cvt_pk_bf16(S[12], S[13]), w1d = cvt_pk_bf16(S[14], S[15]);
        typedef __attribute__((ext_vector_type(4))) unsigned int u32x4t;
        u32x4t pw0 = { w0a, w0b, w0c, w0d };
        u32x4t pw1 = { w1a, w1b, w1c, w1d };
        short8 pf0 = __builtin_bit_cast(short8, pw0);
        short8 pf1 = __builtin_bit_cast(short8, pw1);

        // ---- O^T += V^T P^T (V frags lane-linear 1KB reads: conflict-free) ----
        #pragma unroll
        for (int dt = 0; dt < 4; dt++) {
            short8 vf0 = *(const short8*)(Vb + (dt * 2 + 0) * 512 + lane * 8);
            short8 vf1 = *(const short8*)(Vb + (dt * 2 + 1) * 512 + lane * 8);
            floatx16* Od = (dt == 0) ? &O0 : (dt == 1) ? &O1 : (dt == 2) ? &O2 : &O3;
            *Od = __builtin_amdgcn_mfma_f32_32x32x16_bf16(vf0, pf0, *Od, 0, 0, 0);
            *Od = __builtin_amdgcn_mfma_f32_32x32x16_bf16(vf1, pf1, *Od, 0, 0, 0);
        }
    }

    __syncthreads();   // drain everything; staging LDS is now free for the epilogue

    // ---- epilogue: normalize, transpose O^T -> O via wave-private 2KB LDS bounce ----
    lacc += __shfl_xor(lacc, 32);                  // fold the other key-half (same q on lane^32)
    float inv = __builtin_amdgcn_rcpf(lacc);
    u16* ep = pool + w * 1024;                     // [32 q][32 d] bf16 per dt pass
    const floatx16* Os[4] = { &O0, &O1, &O2, &O3 };
    #pragma unroll
    for (int dt = 0; dt < 4; dt++) {
        #pragma unroll
        for (int g = 0; g < 4; g++) {
            // reg r=g*4+i -> d_local = i + 8g + 4hi, col q=ln
            float a0 = (*Os[dt])[g * 4 + 0] * inv, a1 = (*Os[dt])[g * 4 + 1] * inv;
            float a2 = (*Os[dt])[g * 4 + 2] * inv, a3 = (*Os[dt])[g * 4 + 3] * inv;
            uint2v pk;
            pk[0] = cvt_pk_bf16(a0, a1);
            pk[1] = cvt_pk_bf16(a2, a3);
            *(uint2v*)(ep + ln * 32 + g * 8 + hi * 4) = pk;   // same-wave DS pipe is in-order
        }
        ushort8 r0 = *(const ushort8*)(ep + ln * 32 + hi * 16);
        ushort8 r1 = *(const ushort8*)(ep + ln * 32 + hi * 16 + 8);
        u16* dst = Enc + (size_t)(b * TT + qw + ln) * (NH * HD) + h * HD + dt * 32 + hi * 16;
        *(ushort8*)dst = r0;
        *(ushort8*)(dst + 8) = r1;
    }
}

extern "C" void kernel_launch(void* const* d_in, const int* in_sizes, int n_in,
                              void* d_out, int out_size, void* d_ws, size_t ws_size,
                              hipStream_t stream) {
    const float* x  = (const float*)d_in[0];
    const float* wq = (const float*)d_in[1];
    const float* wk = (const float*)d_in[2];
    const float* wv = (const float*)d_in[3];
    const float* wo = (const float*)d_in[4];
    float* out = (float*)d_out;

    char* ws = (char*)d_ws;
    size_t off = 0;
    auto alloc = [&](size_t bytes) -> void* {
        void* p = ws + off;
        off += (bytes + 255) & ~(size_t)255;
        return p;
    };
    u16* xb    = (u16*)alloc((size_t)BT * CC * 2);
    u16* wqkvT = (u16*)alloc((size_t)SQKV * CC * 2);   // rows: Wq^T 0-2047, Wk^T 2048-2559, Wv^T 2560-3071
    u16* woT   = (u16*)alloc((size_t)CC * CC * 2);
    u16* QKVb  = (u16*)alloc((size_t)BT * SQKV * 2);   // [4096][3072]
    u16* VtT   = (u16*)alloc((size_t)BT * NKV * HD * 2); // [B][NKV][HD][T]
    u16* Enc   = (u16*)alloc((size_t)BT * NH * HD * 2);

    // 1) casts / weight transposes
    cast_bf16_kernel<<<(BT * CC / 4 + 255) / 256, 256, 0, stream>>>(x, xb, BT * CC / 4);
    dim3 tb(32, 8);
    transpose_cast_f32_kernel<<<dim3(CC / 32, CC / 32), tb, 0, stream>>>(wq, wqkvT, CC, CC);
    transpose_cast_f32_kernel<<<dim3(NKV * HD / 32, CC / 32), tb, 0, stream>>>(wk, wqkvT + (size_t)2048 * CC, CC, NKV * HD);
    transpose_cast_f32_kernel<<<dim3(NKV * HD / 32, CC / 32), tb, 0, stream>>>(wv, wqkvT + (size_t)2560 * CC, CC, NKV * HD);
    transpose_cast_f32_kernel<<<dim3(CC / 32, CC / 32), tb, 0, stream>>>(wo, woT, CC, CC);

    // 2) merged QKV projection (N=3072): 128x128 tiles, 8-wave counted-vmcnt GEMM
    gemm128x8_kernel<false><<<dim3(SQKV / 128, BT / 128), 512, 0, stream>>>(xb, wqkvT, QKVb, BT, SQKV, CC);

    // 3) RoPE (scale folded into Q); K at col offset 2048, row stride 3072
    rope_kernel<<<BT * NH, HD, 0, stream>>>(QKVb, NH, SQKV, 0.08838834764831845f);
    rope_kernel<<<BT * NKV, HD, 0, stream>>>(QKVb + 2048, NKV, SQKV, 1.0f);

    // 4) V -> V^T per batch: QKVb cols 2560.. -> [512][T]
    transpose_bf16_kernel<<<dim3(TT / 32, NKV * HD / 32, BB), tb, 0, stream>>>(
        QKVb, VtT, TT, NKV * HD, SQKV, 2560,
        (size_t)TT * SQKV, (size_t)NKV * HD * TT);

    // 5) flash attention: 512 blocks (16 query-blocks x 32 bh), shared K/V tiles per block
    attn_kernel<<<dim3(16, 32), 256, 0, stream>>>(QKVb, VtT, Enc);

    // 6) output projection (fp32 out)
    gemm128x8_kernel<true><<<dim3(CC / 128, BT / 128), 512, 0, stream>>>(Enc, woT, out, BT, CC, CC);
}

// Round 4
// 353.491 us; speedup vs baseline: 1.0275x; 1.0275x over previous
//
#include <hip/hip_runtime.h>
#include <hip/hip_bf16.h>
#include <math.h>

#define BB 2
#define TT 2048
#define CC 2048
#define NH 16
#define NKV 4
#define HD 128
#define BT (BB*TT)
#define WINDOW 1024
#define SQKV 3072   // QKV buffer row stride: Q cols 0-2047, K 2048-2559, V 2560-3071

typedef unsigned short u16;
typedef unsigned int u32;
typedef __attribute__((ext_vector_type(8))) short short8;      // 8 bf16 = 4 VGPRs (MFMA A/B frag)
typedef __attribute__((ext_vector_type(8))) unsigned short ushort8;
typedef __attribute__((ext_vector_type(4))) unsigned short ushort4v;
typedef __attribute__((ext_vector_type(2))) unsigned int uint2v;
typedef __attribute__((ext_vector_type(4))) float floatx4;     // 16x16 MFMA C/D frag
typedef __attribute__((ext_vector_type(16))) float floatx16;   // 32x32 MFMA C/D frag

typedef const __attribute__((address_space(1))) u32* gas_ptr;
typedef __attribute__((address_space(3))) u32* las_ptr;

static __device__ __forceinline__ u16 f2bf(float f) {
    unsigned u = __builtin_bit_cast(unsigned, f);
    return (u16)((u + 0x7fffu + ((u >> 16) & 1u)) >> 16);   // RNE
}
static __device__ __forceinline__ float bf2f(u16 v) {
    unsigned u = ((unsigned)v) << 16;
    return __builtin_bit_cast(float, u);
}

// packed f32x2 -> bf16x2 (RNE), low half = lo, high half = hi
static __device__ __forceinline__ u32 cvt_pk_bf16(float lo, float hi) {
    u32 r;
    asm("v_cvt_pk_bf16_f32 %0, %1, %2" : "=v"(r) : "v"(lo), "v"(hi));
    return r;
}

// softcap+exp: exp(50*tanh(s/50)) = exp2( t*(c0 + c1 t^2 + c2 t^4) ), t=s/50 clamped to [-1,1].
static __device__ __forceinline__ float softcap_exp(float s) {
    float t = s * 0.02f;
    t = fmaxf(-1.0f, fminf(1.0f, t));     // v_med3
    float t2 = t * t;
    float e = t * fmaf(t2, fmaf(t2, 9.617967f, -24.044917f), 72.134752f);
    return __builtin_amdgcn_exp2f(e);
}

// ---------------- elementwise cast fp32 -> bf16 ----------------
__global__ void cast_bf16_kernel(const float* __restrict__ in, u16* __restrict__ out, int n4) {
    int i = blockIdx.x * blockDim.x + threadIdx.x;
    if (i >= n4) return;
    floatx4 v = *(const floatx4*)(in + (size_t)i * 4);
    ushort4v o;
    o[0] = f2bf(v[0]); o[1] = f2bf(v[1]); o[2] = f2bf(v[2]); o[3] = f2bf(v[3]);
    *(ushort4v*)(out + (size_t)i * 4) = o;
}

// ---------------- transpose + cast fp32 [R][Cc] -> bf16 [Cc][R] ----------------
__global__ void transpose_cast_f32_kernel(const float* __restrict__ in, u16* __restrict__ out,
                                          int R, int Cc) {
    __shared__ u16 tile[32][33];
    int c0 = blockIdx.x * 32, r0 = blockIdx.y * 32;
    int tx = threadIdx.x, ty = threadIdx.y;   // block (32, 8)
    #pragma unroll
    for (int i = 0; i < 4; i++) {
        int r = r0 + ty + i * 8;
        tile[ty + i * 8][tx] = f2bf(in[(size_t)r * Cc + c0 + tx]);
    }
    __syncthreads();
    #pragma unroll
    for (int i = 0; i < 4; i++) {
        int c = c0 + ty + i * 8;
        out[(size_t)c * R + r0 + tx] = tile[tx][ty + i * 8];
    }
}

// ---------------- strided transpose bf16: in[r][colOff + c] -> out [Cc][R], batched z ----------------
__global__ void transpose_bf16_kernel(const u16* __restrict__ in, u16* __restrict__ out,
                                      int R, int Cc, int inStride, int colOff,
                                      size_t inBatchStride, size_t outBatchStride) {
    __shared__ u16 tile[32][33];
    int b = blockIdx.z;
    const u16* inb = in + (size_t)b * inBatchStride;
    u16* outb = out + (size_t)b * outBatchStride;
    int c0 = blockIdx.y * 32, r0 = blockIdx.x * 32;
    int tx = threadIdx.x, ty = threadIdx.y;   // block (32, 8)
    #pragma unroll
    for (int i = 0; i < 4; i++) {
        int r = r0 + ty + i * 8;
        tile[ty + i * 8][tx] = inb[(size_t)r * inStride + colOff + c0 + tx];
    }
    __syncthreads();
    #pragma unroll
    for (int i = 0; i < 4; i++) {
        int c = c0 + ty + i * 8;
        outb[(size_t)c * R + r0 + tx] = tile[tx][ty + i * 8];
    }
}

// ---------------- RoPE in-place on rows of `rowStride` elems, H heads x 128, fold scale ----------------
__global__ void rope_kernel(u16* __restrict__ buf, int H, int rowStride, float scale) {
    int idx = blockIdx.x;                 // bt*H + h
    int bt = idx / H, h = idx - bt * H;
    int t = bt % TT;
    int d = threadIdx.x;                  // 0..127
    u16* p = buf + (size_t)bt * rowStride + h * HD;
    float x  = bf2f(p[d]);
    float xp = bf2f(p[d ^ 64]);
    int j = d & 63;
    float inv = exp2f(-0.20762050593046f * (float)j);   // 10000^(-j/64)
    float ang = (float)t * inv;
    float s, c;
    sincosf(ang, &s, &c);
    float rot = (d < 64) ? -xp : xp;
    float o = (x * c + rot * s) * scale;
    __syncthreads();                      // all reads done before any write
    p[d] = f2bf(o);
}

// ---------------- GEMM v3: 128x256 tile, 8 waves, BK=64, deep-pipelined phases ----------------
// C[M][N] = A[M][K] * Bt[N][K]^T (bf16 in, fp32 acc). 512 thr = 8 waves (2M x 4N), wave-tile 64x64.
// LDS: 2 buffers x 48KB, frag-major: A groups (mf*2+ks)*1KB [16KB] | B at +16KB, (nf*2+ks)*1KB [32KB].
// Group = 64 lanes x 16B, lane l holds mat[row 16g+(l&15)][k = ks*32+(l>>4)*8 ..+8] = exact MFMA frag
// => every ds_read_b128 is lane-consecutive 16B: zero bank conflicts (verified R3).
// Phase X = (tile t=X>>1, ksub ks=X&1). Ring of 4 slots (buffer t&1, ks). Per phase:
//   { 8x ds_read (slot X) ; stage slot X+3 (3 DMA/thread) ; lgkmcnt(0) ; 16 MFMA ; vmcnt(6) ; barrier }
// The vmcnt BEFORE the barrier certifies, for every wave, that the stage issued 3 phases ago
// (= slot X+1, the next phase's reads) has landed: outstanding = stages of phases X, X-1 = 6.
// Prefetch distance = 3 phases (~900cy). Never drains to 0 until the 3-phase tail (6 -> 3 -> 0).
template <bool OUT_F32>
__global__ __launch_bounds__(512, 2) void gemm256_kernel(const u16* __restrict__ A,
                                                         const u16* __restrict__ Bt,
                                                         void* __restrict__ Cout,
                                                         int M, int N, int K) {
    __shared__ alignas(16) u16 lds[2 * 24576];   // 96KB
    int tid = threadIdx.x;
    int w = tid >> 6, lane = tid & 63, quad = lane >> 4, ln = lane & 15;
    int wm = w >> 2, wn = w & 3;                 // wave tile: rows wm*64, cols wn*64

    // bijective XCD swizzle (both grids are multiples of 8)
    int gx = gridDim.x;
    int bid = blockIdx.y * gx + blockIdx.x;
    int cpx = (gx * gridDim.y) >> 3;
    int swz = (bid & 7) * cpx + (bid >> 3);
    int m0 = (swz / gx) * 128;
    int n0 = (swz - (swz / gx) * gx) * 256;

    // per-thread DMA sources: wave w stages A group mf=w, B groups nf=w and nf=8+w
    const u16* pA  = A  + (size_t)(m0 + w * 16 + ln) * K + quad * 8;
    const u16* pB0 = Bt + (size_t)(n0 + w * 16 + ln) * K + quad * 8;
    const u16* pB1 = Bt + (size_t)(n0 + (8 + w) * 16 + ln) * K + quad * 8;
    int dA  = w * 1024 + lane * 8;               // u16 offsets (+ ks*512 + buffer)
    int dB0 = 8192 + w * 1024 + lane * 8;
    int dB1 = 8192 + (8 + w) * 1024 + lane * 8;

    int aoff = wm * 4096 + lane * 8;             // A frag base: mf = wm*4
    int boff = 8192 + wn * 4096 + lane * 8;      // B frag base: nf = wn*4

    floatx4 acc[4][4] = {};
    const int nk = K >> 6;                       // K-tiles of 64 (nk >= 3)

    auto stage = [&](int Y) {                    // stage slot for phase Y
        int ty = Y >> 1, ks = Y & 1;
        int koff = ty * 64 + ks * 32;
        int bufo = (ty & 1) * 24576 + ks * 512;
        __builtin_amdgcn_global_load_lds((gas_ptr)(pA  + koff), (las_ptr)(lds + bufo + dA),  16, 0, 0);
        __builtin_amdgcn_global_load_lds((gas_ptr)(pB0 + koff), (las_ptr)(lds + bufo + dB0), 16, 0, 0);
        __builtin_amdgcn_global_load_lds((gas_ptr)(pB1 + koff), (las_ptr)(lds + bufo + dB1), 16, 0, 0);
    };

    auto phase = [&](int t, int ks, int wait, bool doStage, bool doBar) {
        const u16* buf = lds + (t & 1) * 24576 + ks * 512;
        short8 af[4], bf[4];
        #pragma unroll
        for (int m = 0; m < 4; m++) af[m] = *(const short8*)(buf + aoff + m * 1024);
        #pragma unroll
        for (int n = 0; n < 4; n++) bf[n] = *(const short8*)(buf + boff + n * 1024);
        if (doStage) stage(2 * t + ks + 3);      // targets slot read last phase (barrier-protected)
        __builtin_amdgcn_s_waitcnt(0xC07F);      // lgkmcnt(0): own frag reads done
        __builtin_amdgcn_sched_barrier(0);
        __builtin_amdgcn_s_setprio(1);
        #pragma unroll
        for (int m = 0; m < 4; m++)
            #pragma unroll
            for (int n = 0; n < 4; n++)
                acc[m][n] = __builtin_amdgcn_mfma_f32_16x16x32_bf16(af[m], bf[n], acc[m][n], 0, 0, 0);
        __builtin_amdgcn_s_setprio(0);
        __builtin_amdgcn_sched_barrier(0);
        if (wait == 6)      __builtin_amdgcn_s_waitcnt(0x0F76);   // certify slot X+1 (3-phase-old stage)
        else if (wait == 3) __builtin_amdgcn_s_waitcnt(0x0F73);
        else if (wait == 0) __builtin_amdgcn_s_waitcnt(0x0F70);
        __builtin_amdgcn_sched_barrier(0);
        if (doBar) __builtin_amdgcn_s_barrier();                  // all waves certified + done reading
        __builtin_amdgcn_sched_barrier(0);
    };

    // prologue: slots for phases 0,1,2 (9 loads/thread); certify slot 0 for all waves
    stage(0); stage(1); stage(2);
    __builtin_amdgcn_s_waitcnt(0x0F76);
    __builtin_amdgcn_sched_barrier(0);
    __builtin_amdgcn_s_barrier();
    __builtin_amdgcn_sched_barrier(0);

    for (int t = 0; t < nk - 2; ++t) {
        phase(t, 0, 6, true, true);
        phase(t, 1, 6, true, true);
    }
    phase(nk - 2, 0, 6, true,  true);    // last stage (slot 2nk-1)
    phase(nk - 2, 1, 3, false, true);    // certify slot 2nk-2
    phase(nk - 1, 0, 0, false, true);    // certify slot 2nk-1
    phase(nk - 1, 1, -1, false, false);  // final phase, straight to epilogue

    #pragma unroll
    for (int m = 0; m < 4; m++)
      #pragma unroll
      for (int n = 0; n < 4; n++)
        #pragma unroll
        for (int r = 0; r < 4; r++) {
            size_t row = m0 + wm * 64 + m * 16 + quad * 4 + r;
            size_t col = n0 + wn * 64 + n * 16 + ln;
            float v = acc[m][n][r];
            if (OUT_F32) ((float*)Cout)[row * N + col] = v;
            else         ((u16*)Cout)[row * N + col] = f2bf(v);
        }
}

// ---------------- flash attention v3: shared K/V tiles, 128-query blocks ----------------
// Block = 128 queries x (b,h), 4 waves each owning 32 queries. All waves iterate the SAME key
// tiles; K/V staged in LDS once per block via global_load_lds (16 x 1KB DMA, 4 per wave),
// double-buffered with one-tile-ahead prefetch. Raw s_barrier + counted vmcnt(4).
// LDS layout = read order: every ds_read_b128 is lane-linear over a contiguous 1KB group =>
// conflict-free. In-register softmax via sigma-permuted K rows + cvt_pk P-pack:
//   sigma(m) = (m&3) + 4*bit3(m) + 8*bit2(m) + 16*bit4(m)
//   S^T reg r holds key s0 + (r&3) + 4*((r>>2)&1) + 8*hi + 16*(r>>3), col q = ln.
__global__ __launch_bounds__(256, 2) void attn_kernel(const u16* __restrict__ QKV,
                                                      const u16* __restrict__ Vt,
                                                      u16* __restrict__ Enc) {
    // buf[2] x { K: 8KB (groups ks=0..7, 1KB each) | V: 8KB (groups g=dt*2+half) } = 32KB
    __shared__ alignas(16) u16 pool[2 * 8192];

    int tid = threadIdx.x;
    int w = tid >> 6, lane = tid & 63, hi = lane >> 5, ln = lane & 31;
    int hi8 = hi * 8;

    int qb = (15 - (int)blockIdx.x) * 128;      // long blocks first
    int bh = blockIdx.y;
    int b = bh >> 4, h = bh & 15, kh = h >> 2;
    int qw = qb + w * 32;                        // this wave's query base

    // Q B-frag [n=q=ln][k=hi*8 + ks*16 + j]
    short8 qf[8];
    {
        const u16* qptr = QKV + (size_t)(b * TT + qw + ln) * SQKV + h * HD + hi8;
        #pragma unroll
        for (int ks = 0; ks < 8; ks++) qf[ks] = *(const short8*)(qptr + ks * 16);
    }

    // ---- DMA source setup: wave w issues groups [w*4, w*4+4) of {K0..7, V0..7} ----
    int sig = (ln & 3) + (((ln >> 3) & 1) << 2) + (((ln >> 2) & 1) << 3) + ((ln >> 4) << 4);
    bool isK = (w < 2);
    const u16* dsrc[4];
    int ldst[4];                                 // u16 offset within a 16KB buffer
    #pragma unroll
    for (int i = 0; i < 4; i++) {
        if (isK) {
            int ks = w * 4 + i;
            dsrc[i] = QKV + (size_t)(b * TT + sig) * SQKV + 2048 + kh * HD + ks * 16 + hi8;
            ldst[i] = ks * 512;
        } else {
            int g = (w - 2) * 4 + i;
            dsrc[i] = Vt + (size_t)((b * NKV + kh) * HD + (g >> 1) * 32 + ln) * TT + (g & 1) * 16 + hi8;
            ldst[i] = 4096 + g * 512;
        }
    }
    size_t addmul = isK ? (size_t)SQKV : (size_t)1;

    floatx16 O0 = {}, O1 = {}, O2 = {}, O3 = {};   // O^T d-tiles: D[m=d][n=q]
    float lacc = 0.0f;

    int S_LO = qb - WINDOW; if (S_LO < 0) S_LO = 0;
    int nt = (qb + 128 - S_LO) >> 5;

    auto issue = [&](int t) {
        int s0 = S_LO + t * 32;
        u16* base = pool + (t & 1) * 8192;
        size_t add = (size_t)s0 * addmul;
        #pragma unroll
        for (int i = 0; i < 4; i++)
            __builtin_amdgcn_global_load_lds((gas_ptr)(dsrc[i] + add), (las_ptr)(base + ldst[i]), 16, 0, 0);
    };

    issue(0);
    for (int t = 0; t < nt; ++t) {
        // barrier A: all waves done reading buf[(t+1)&1] (= tile t-1's buffer)
        __builtin_amdgcn_sched_barrier(0);
        __builtin_amdgcn_s_barrier();
        __builtin_amdgcn_sched_barrier(0);
        if (t + 1 < nt) {
            issue(t + 1);
            __builtin_amdgcn_sched_barrier(0);
            __builtin_amdgcn_s_waitcnt(0x0F74);   // vmcnt(4): own tile-t DMAs landed, t+1 in flight
        } else {
            __builtin_amdgcn_s_waitcnt(0x0F70);   // vmcnt(0): last tile, drain all
        }
        __builtin_amdgcn_sched_barrier(0);
        __builtin_amdgcn_s_barrier();             // barrier B: ALL waves' tile-t data in LDS
        __builtin_amdgcn_sched_barrier(0);

        int s0 = S_LO + t * 32;
        if (s0 > qw + 31 || s0 + 31 < qw - WINDOW) continue;   // tile outside this wave's window

        const u16* Kb = pool + (t & 1) * 8192;
        const u16* Vb = Kb + 4096;

        // ---- S^T = K Q^T (rows = sigma-permuted keys, cols = q) ----
        floatx16 S = {};
        #pragma unroll
        for (int ks = 0; ks < 8; ks++) {
            short8 kf = *(const short8*)(Kb + ks * 512 + lane * 8);   // lane-linear: conflict-free
            S = __builtin_amdgcn_mfma_f32_32x32x16_bf16(kf, qf[ks], S, 0, 0, 0);
        }

        // ---- softcap + exp (+ mask only on edge tiles), in place ----
        bool full = (s0 + 31 <= qw) && (s0 >= qw + 31 - WINDOW);
        if (full) {
            #pragma unroll
            for (int r = 0; r < 16; r++) S[r] = softcap_exp(S[r]);
        } else {
            int tq = qw + ln;
            #pragma unroll
            for (int r = 0; r < 16; r++) {
                int s = s0 + (r & 3) + (((r >> 2) & 1) << 2) + hi8 + ((r >> 3) << 4);
                bool good = (s <= tq) && (s >= tq - WINDOW);
                S[r] = good ? softcap_exp(S[r]) : 0.0f;
            }
        }

        // ---- own-half l accumulation (tree) ----
        lacc += ((((S[0] + S[1]) + (S[2] + S[3])) + ((S[4] + S[5]) + (S[6] + S[7])))
               + (((S[8] + S[9]) + (S[10] + S[11])) + ((S[12] + S[13]) + (S[14] + S[15]))));

        // ---- pack P -> bf16 B-frags (already frag-ordered thanks to sigma) ----
        u32 w0a = cvt_pk_bf16(S[0],  S[1]),  w0b = cvt_pk_bf16(S[2],  S[3]);
        u32 w0c = cvt_pk_bf16(S[4],  S[5]),  w0d = cvt_pk_bf16(S[6],  S[7]);
        u32 w1a = cvt_pk_bf16(S[8],  S[9]),  w1b = cvt_pk_bf16(S[10], S[11]);
        u32 w1c = cvt_pk_bf16(S[12], S[13]), w1d = cvt_pk_bf16(S[14], S[15]);
        typedef __attribute__((ext_vector_type(4))) unsigned int u32x4t;
        u32x4t pw0 = { w0a, w0b, w0c, w0d };
        u32x4t pw1 = { w1a, w1b, w1c, w1d };
        short8 pf0 = __builtin_bit_cast(short8, pw0);
        short8 pf1 = __builtin_bit_cast(short8, pw1);

        // ---- O^T += V^T P^T (V frags lane-linear 1KB reads: conflict-free) ----
        #pragma unroll
        for (int dt = 0; dt < 4; dt++) {
            short8 vf0 = *(const short8*)(Vb + (dt * 2 + 0) * 512 + lane * 8);
            short8 vf1 = *(const short8*)(Vb + (dt * 2 + 1) * 512 + lane * 8);
            floatx16* Od = (dt == 0) ? &O0 : (dt == 1) ? &O1 : (dt == 2) ? &O2 : &O3;
            *Od = __builtin_amdgcn_mfma_f32_32x32x16_bf16(vf0, pf0, *Od, 0, 0, 0);
            *Od = __builtin_amdgcn_mfma_f32_32x32x16_bf16(vf1, pf1, *Od, 0, 0, 0);
        }
    }

    __syncthreads();   // drain everything; staging LDS is now free for the epilogue

    // ---- epilogue: normalize, transpose O^T -> O via wave-private 2KB LDS bounce ----
    lacc += __shfl_xor(lacc, 32);                  // fold the other key-half (same q on lane^32)
    float inv = __builtin_amdgcn_rcpf(lacc);
    u16* ep = pool + w * 1024;                     // [32 q][32 d] bf16 per dt pass
    const floatx16* Os[4] = { &O0, &O1, &O2, &O3 };
    #pragma unroll
    for (int dt = 0; dt < 4; dt++) {
        #pragma unroll
        for (int g = 0; g < 4; g++) {
            // reg r=g*4+i -> d_local = i + 8g + 4hi, col q=ln
            float a0 = (*Os[dt])[g * 4 + 0] * inv, a1 = (*Os[dt])[g * 4 + 1] * inv;
            float a2 = (*Os[dt])[g * 4 + 2] * inv, a3 = (*Os[dt])[g * 4 + 3] * inv;
            uint2v pk;
            pk[0] = cvt_pk_bf16(a0, a1);
            pk[1] = cvt_pk_bf16(a2, a3);
            *(uint2v*)(ep + ln * 32 + g * 8 + hi * 4) = pk;   // same-wave DS pipe is in-order
        }
        ushort8 r0 = *(const ushort8*)(ep + ln * 32 + hi * 16);
        ushort8 r1 = *(const ushort8*)(ep + ln * 32 + hi * 16 + 8);
        u16* dst = Enc + (size_t)(b * TT + qw + ln) * (NH * HD) + h * HD + dt * 32 + hi * 16;
        *(ushort8*)dst = r0;
        *(ushort8*)(dst + 8) = r1;
    }
}

extern "C" void kernel_launch(void* const* d_in, const int* in_sizes, int n_in,
                              void* d_out, int out_size, void* d_ws, size_t ws_size,
                              hipStream_t stream) {
    const float* x  = (const float*)d_in[0];
    const float* wq = (const float*)d_in[1];
    const float* wk = (const float*)d_in[2];
    const float* wv = (const float*)d_in[3];
    const float* wo = (const float*)d_in[4];
    float* out = (float*)d_out;

    char* ws = (char*)d_ws;
    size_t off = 0;
    auto alloc = [&](size_t bytes) -> void* {
        void* p = ws + off;
        off += (bytes + 255) & ~(size_t)255;
        return p;
    };
    u16* xb    = (u16*)alloc((size_t)BT * CC * 2);
    u16* wqkvT = (u16*)alloc((size_t)SQKV * CC * 2);   // rows: Wq^T 0-2047, Wk^T 2048-2559, Wv^T 2560-3071
    u16* woT   = (u16*)alloc((size_t)CC * CC * 2);
    u16* QKVb  = (u16*)alloc((size_t)BT * SQKV * 2);   // [4096][3072]
    u16* VtT   = (u16*)alloc((size_t)BT * NKV * HD * 2); // [B][NKV][HD][T]
    u16* Enc   = (u16*)alloc((size_t)BT * NH * HD * 2);

    // 1) casts / weight transposes
    cast_bf16_kernel<<<(BT * CC / 4 + 255) / 256, 256, 0, stream>>>(x, xb, BT * CC / 4);
    dim3 tb(32, 8);
    transpose_cast_f32_kernel<<<dim3(CC / 32, CC / 32), tb, 0, stream>>>(wq, wqkvT, CC, CC);
    transpose_cast_f32_kernel<<<dim3(NKV * HD / 32, CC / 32), tb, 0, stream>>>(wk, wqkvT + (size_t)2048 * CC, CC, NKV * HD);
    transpose_cast_f32_kernel<<<dim3(NKV * HD / 32, CC / 32), tb, 0, stream>>>(wv, wqkvT + (size_t)2560 * CC, CC, NKV * HD);
    transpose_cast_f32_kernel<<<dim3(CC / 32, CC / 32), tb, 0, stream>>>(wo, woT, CC, CC);

    // 2) merged QKV projection (N=3072): 128x256 tiles, deep-pipelined GEMM (384 blocks)
    gemm256_kernel<false><<<dim3(SQKV / 256, BT / 128), 512, 0, stream>>>(xb, wqkvT, QKVb, BT, SQKV, CC);

    // 3) RoPE (scale folded into Q); K at col offset 2048, row stride 3072
    rope_kernel<<<BT * NH, HD, 0, stream>>>(QKVb, NH, SQKV, 0.08838834764831845f);
    rope_kernel<<<BT * NKV, HD, 0, stream>>>(QKVb + 2048, NKV, SQKV, 1.0f);

    // 4) V -> V^T per batch: QKVb cols 2560.. -> [512][T]
    transpose_bf16_kernel<<<dim3(TT / 32, NKV * HD / 32, BB), tb, 0, stream>>>(
        QKVb, VtT, TT, NKV * HD, SQKV, 2560,
        (size_t)TT * SQKV, (size_t)NKV * HD * TT);

    // 5) flash attention: 512 blocks (16 query-blocks x 32 bh), shared K/V tiles per block
    attn_kernel<<<dim3(16, 32), 256, 0, stream>>>(QKVb, VtT, Enc);

    // 6) output projection (fp32 out): 128x256 tiles (256 blocks = 1/CU)
    gemm256_kernel<true><<<dim3(CC / 256, BT / 128), 512, 0, stream>>>(Enc, woT, out, BT, CC, CC);
}

// Round 5
// 330.088 us; speedup vs baseline: 1.1004x; 1.0709x over previous
//
#include <hip/hip_runtime.h>
#include <hip/hip_bf16.h>
#include <math.h>

#define BB 2
#define TT 2048
#define CC 2048
#define NH 16
#define NKV 4
#define HD 128
#define BT (BB*TT)
#define WINDOW 1024
#define SQKV 3072   // QKV buffer row stride: Q cols 0-2047, K 2048-2559, V 2560-3071

typedef unsigned short u16;
typedef unsigned int u32;
typedef __attribute__((ext_vector_type(8))) short short8;      // 8 bf16 = 4 VGPRs (MFMA A/B frag)
typedef __attribute__((ext_vector_type(8))) unsigned short ushort8;
typedef __attribute__((ext_vector_type(4))) unsigned short ushort4v;
typedef __attribute__((ext_vector_type(2))) unsigned int uint2v;
typedef __attribute__((ext_vector_type(4))) float floatx4;     // 16x16 MFMA C/D frag
typedef __attribute__((ext_vector_type(16))) float floatx16;   // 32x32 MFMA C/D frag

typedef const __attribute__((address_space(1))) u32* gas_ptr;
typedef __attribute__((address_space(3))) u32* las_ptr;

static __device__ __forceinline__ u16 f2bf(float f) {
    unsigned u = __builtin_bit_cast(unsigned, f);
    return (u16)((u + 0x7fffu + ((u >> 16) & 1u)) >> 16);   // RNE
}
static __device__ __forceinline__ float bf2f(u16 v) {
    unsigned u = ((unsigned)v) << 16;
    return __builtin_bit_cast(float, u);
}

// packed f32x2 -> bf16x2 (RNE), low half = lo, high half = hi
static __device__ __forceinline__ u32 cvt_pk_bf16(float lo, float hi) {
    u32 r;
    asm("v_cvt_pk_bf16_f32 %0, %1, %2" : "=v"(r) : "v"(lo), "v"(hi));
    return r;
}

// softcap+exp: exp(50*tanh(s/50)) = exp2( t*(c0 + c1 t^2 + c2 t^4) ), t=s/50 clamped to [-1,1].
static __device__ __forceinline__ float softcap_exp(float s) {
    float t = s * 0.02f;
    t = fmaxf(-1.0f, fminf(1.0f, t));     // v_med3
    float t2 = t * t;
    float e = t * fmaf(t2, fmaf(t2, 9.617967f, -24.044917f), 72.134752f);
    return __builtin_amdgcn_exp2f(e);
}

// ---------------- elementwise cast fp32 -> bf16 ----------------
__global__ void cast_bf16_kernel(const float* __restrict__ in, u16* __restrict__ out, int n4) {
    int i = blockIdx.x * blockDim.x + threadIdx.x;
    if (i >= n4) return;
    floatx4 v = *(const floatx4*)(in + (size_t)i * 4);
    ushort4v o;
    o[0] = f2bf(v[0]); o[1] = f2bf(v[1]); o[2] = f2bf(v[2]); o[3] = f2bf(v[3]);
    *(ushort4v*)(out + (size_t)i * 4) = o;
}

// ---------------- transpose + cast fp32 [R][Cc] -> bf16 [Cc][R] ----------------
__global__ void transpose_cast_f32_kernel(const float* __restrict__ in, u16* __restrict__ out,
                                          int R, int Cc) {
    __shared__ u16 tile[32][33];
    int c0 = blockIdx.x * 32, r0 = blockIdx.y * 32;
    int tx = threadIdx.x, ty = threadIdx.y;   // block (32, 8)
    #pragma unroll
    for (int i = 0; i < 4; i++) {
        int r = r0 + ty + i * 8;
        tile[ty + i * 8][tx] = f2bf(in[(size_t)r * Cc + c0 + tx]);
    }
    __syncthreads();
    #pragma unroll
    for (int i = 0; i < 4; i++) {
        int c = c0 + ty + i * 8;
        out[(size_t)c * R + r0 + tx] = tile[tx][ty + i * 8];
    }
}

// ---------------- strided transpose bf16: in[r][colOff + c] -> out [Cc][R], batched z ----------------
__global__ void transpose_bf16_kernel(const u16* __restrict__ in, u16* __restrict__ out,
                                      int R, int Cc, int inStride, int colOff,
                                      size_t inBatchStride, size_t outBatchStride) {
    __shared__ u16 tile[32][33];
    int b = blockIdx.z;
    const u16* inb = in + (size_t)b * inBatchStride;
    u16* outb = out + (size_t)b * outBatchStride;
    int c0 = blockIdx.y * 32, r0 = blockIdx.x * 32;
    int tx = threadIdx.x, ty = threadIdx.y;   // block (32, 8)
    #pragma unroll
    for (int i = 0; i < 4; i++) {
        int r = r0 + ty + i * 8;
        tile[ty + i * 8][tx] = inb[(size_t)r * inStride + colOff + c0 + tx];
    }
    __syncthreads();
    #pragma unroll
    for (int i = 0; i < 4; i++) {
        int c = c0 + ty + i * 8;
        outb[(size_t)c * R + r0 + tx] = tile[tx][ty + i * 8];
    }
}

// ---------------- RoPE in-place on rows of `rowStride` elems, H heads x 128, fold scale ----------------
__global__ void rope_kernel(u16* __restrict__ buf, int H, int rowStride, float scale) {
    int idx = blockIdx.x;                 // bt*H + h
    int bt = idx / H, h = idx - bt * H;
    int t = bt % TT;
    int d = threadIdx.x;                  // 0..127
    u16* p = buf + (size_t)bt * rowStride + h * HD;
    float x  = bf2f(p[d]);
    float xp = bf2f(p[d ^ 64]);
    int j = d & 63;
    float inv = exp2f(-0.20762050593046f * (float)j);   // 10000^(-j/64)
    float ang = (float)t * inv;
    float s, c;
    sincosf(ang, &s, &c);
    float rot = (d < 64) ? -xp : xp;
    float o = (x * c + rot * s) * scale;
    __syncthreads();                      // all reads done before any write
    p[d] = f2bf(o);
}

// ---------------- m97-style GEMM: C[M][N] = A[M][K] * Bt[N][K]^T (bf16 in, fp32 acc) ----------------
// Proven at ~700 TF on this workload (R2). Used for the output projection.
template <bool OUT_F32>
__global__ __launch_bounds__(256) void gemm128_kernel(const u16* __restrict__ A,
                                                      const u16* __restrict__ Bt,
                                                      void* __restrict__ Cout,
                                                      int M, int N, int K) {
    __shared__ alignas(16) u16 As[128 * 32];   // row-major [128][32], NO padding (lds-dma layout)
    __shared__ alignas(16) u16 Bs[128 * 32];
    int tid = threadIdx.x;
    int w = tid >> 6, lane = tid & 63, quad = lane >> 4, ln = lane & 15;
    int m0 = blockIdx.y * 128;
    int n0 = blockIdx.x * 128;
    int wm = (w >> 1) * 64;
    int wn = (w & 1) * 64;

    int o0 = (w * 2) * 1024 + lane * 16;
    int row0 = o0 >> 6, kc0 = (o0 & 63) >> 4;
    int o1 = o0 + 1024;
    int row1 = o1 >> 6, kc1 = (o1 & 63) >> 4;
    const u16* gA0 = A  + (size_t)(m0 + row0) * K + kc0 * 8;
    const u16* gA1 = A  + (size_t)(m0 + row1) * K + kc1 * 8;
    const u16* gB0 = Bt + (size_t)(n0 + row0) * K + kc0 * 8;
    const u16* gB1 = Bt + (size_t)(n0 + row1) * K + kc1 * 8;
    u16* lA0 = As + (w * 2) * 512;
    u16* lA1 = As + (w * 2 + 1) * 512;
    u16* lB0 = Bs + (w * 2) * 512;
    u16* lB1 = Bs + (w * 2 + 1) * 512;

    floatx4 acc[4][4] = {};

    for (int k0 = 0; k0 < K; k0 += 32) {
        __syncthreads();
        __builtin_amdgcn_global_load_lds((gas_ptr)(gA0 + k0), (las_ptr)lA0, 16, 0, 0);
        __builtin_amdgcn_global_load_lds((gas_ptr)(gA1 + k0), (las_ptr)lA1, 16, 0, 0);
        __builtin_amdgcn_global_load_lds((gas_ptr)(gB0 + k0), (las_ptr)lB0, 16, 0, 0);
        __builtin_amdgcn_global_load_lds((gas_ptr)(gB1 + k0), (las_ptr)lB1, 16, 0, 0);
        __syncthreads();

        short8 af[4], bf[4];
        #pragma unroll
        for (int mt = 0; mt < 4; mt++)
            af[mt] = *(const short8*)(As + (wm + mt * 16 + ln) * 32 + quad * 8);
        #pragma unroll
        for (int nt = 0; nt < 4; nt++)
            bf[nt] = *(const short8*)(Bs + (wn + nt * 16 + ln) * 32 + quad * 8);
        #pragma unroll
        for (int mt = 0; mt < 4; mt++)
            #pragma unroll
            for (int nt = 0; nt < 4; nt++)
                acc[mt][nt] = __builtin_amdgcn_mfma_f32_16x16x32_bf16(af[mt], bf[nt], acc[mt][nt], 0, 0, 0);
    }

    #pragma unroll
    for (int mt = 0; mt < 4; mt++)
      #pragma unroll
      for (int nt = 0; nt < 4; nt++)
        #pragma unroll
        for (int r = 0; r < 4; r++) {
            size_t row = m0 + wm + mt * 16 + quad * 4 + r;
            size_t col = n0 + wn + nt * 16 + ln;
            float v = acc[mt][nt][r];
            if (OUT_F32) ((float*)Cout)[row * N + col] = v;
            else         ((u16*)Cout)[row * N + col] = f2bf(v);
        }
}

// ---------------- GEMM 256sq: faithful 8-phase/iter (4-phase/K-tile) 256x256 template ----------------
// C = A * Bt^T, BM=BN=256, BK=64, 8 waves (2M x 4N), wave-tile 128x64, acc 8x4 frags (128 VGPR).
// LDS 2 x 64KB frag-major: per buffer { A-ks0 | B-ks0 | A-ks1 | B-ks1 } x 16KB; each region = 16
// groups of 1KB = one MFMA fragment (lane l: row f*16+(l&15), k = ks*32+(l>>4)*8) -> every
// ds_read_b128 lane-linear, zero conflicts (verified R3/R4).
// K-tile = 4 phases (mh, ks): ph(0,ks)=8 reads (4 A + 4 B), ph(1,ks)=4 reads (B held in regs).
// Each phase stages ONE half-tile (2 DMA/wave) of tile t+1, order {A-ks0,B-ks0,A-ks1,B-ks1}:
// stage-to-use distance 3-4 phases. Wait ledger (loads/wave): outstanding peaks at 8;
// vmcnt(4)+barrier at ends of ph1 and ph3 certify exactly the half-tiles read next phase.
// Never drains below 4 in the loop; only 2 barriers per K-tile.
template <bool OUT_F32>
__global__ __launch_bounds__(512, 1) void gemm256sq_kernel(const u16* __restrict__ A,
                                                           const u16* __restrict__ Bt,
                                                           void* __restrict__ Cout,
                                                           int M, int N, int K) {
    __shared__ alignas(16) u16 lds[2 * 32768];   // 128KB
    int tid = threadIdx.x;
    int w = tid >> 6, lane = tid & 63, quad = lane >> 4, ln = lane & 15;
    int wm = w >> 2, wn = w & 3;                 // wave tile: rows wm*128, cols wn*64

    // bijective XCD swizzle (grid size % 8 == 0)
    int gx = gridDim.x;
    int bid = blockIdx.y * gx + blockIdx.x;
    int cpx = (gx * gridDim.y) >> 3;
    int swz = (bid & 7) * cpx + (bid >> 3);
    int m0 = (swz / gx) * 256;
    int n0 = (swz - (swz / gx) * gx) * 256;

    // DMA sources: wave w stages frag-groups {w, w+8} of each half-tile
    const u16* srcA0 = A  + (size_t)(m0 + w * 16 + ln) * K + quad * 8;          // group w
    const u16* srcA1 = A  + (size_t)(m0 + 128 + w * 16 + ln) * K + quad * 8;    // group w+8
    const u16* srcB0 = Bt + (size_t)(n0 + w * 16 + ln) * K + quad * 8;
    const u16* srcB1 = Bt + (size_t)(n0 + 128 + w * 16 + ln) * K + quad * 8;
    int dst0 = w * 512 + lane * 8;               // u16 offset within region (+4096 for group w+8)

    floatx4 acc[8][4] = {};
    short8 bfr[4];                               // B frags held across the two mh-phases of a ks
    const int nk = K >> 6;

    // stage half-tile ht of K-tile t: ht 0=A-ks0, 1=B-ks0, 2=A-ks1, 3=B-ks1 (region = ht*8192)
    auto stage = [&](int t, int ht) {
        int ks = ht >> 1;
        int ko = t * 64 + ks * 32;
        const u16* s0 = (ht & 1) ? srcB0 : srcA0;
        const u16* s1 = (ht & 1) ? srcB1 : srcA1;
        u16* d = lds + (t & 1) * 32768 + ht * 8192 + dst0;
        __builtin_amdgcn_global_load_lds((gas_ptr)(s0 + ko), (las_ptr)(d), 16, 0, 0);
        __builtin_amdgcn_global_load_lds((gas_ptr)(s1 + ko), (las_ptr)(d + 4096), 16, 0, 0);
    };

    // one phase: quadrant (mh, ks) of K-tile t; stht = half-tile of t+1 to stage (-1 none);
    // wait = vmcnt N before barrier (-1 none); bar = emit s_barrier
    auto phase = [&](int t, int mh, int ks, int stht, int wait, bool bar) {
        const u16* buf = lds + (t & 1) * 32768;
        const u16* Ar = buf + ks * 16384 + (wm * 8 + mh * 4) * 512 + lane * 8;
        const u16* Br = buf + 8192 + ks * 16384 + (wn * 4) * 512 + lane * 8;
        short8 af[4];
        #pragma unroll
        for (int m = 0; m < 4; m++) af[m] = *(const short8*)(Ar + m * 512);
        if (mh == 0) {
            #pragma unroll
            for (int n = 0; n < 4; n++) bfr[n] = *(const short8*)(Br + n * 512);
        }
        if (stht >= 0) stage(t + 1, stht);
        __builtin_amdgcn_s_waitcnt(0xC07F);      // lgkmcnt(0): own frag reads done
        __builtin_amdgcn_sched_barrier(0);       // rule #18: pin MFMA after the wait
        __builtin_amdgcn_s_setprio(1);
        #pragma unroll
        for (int m = 0; m < 4; m++)
            #pragma unroll
            for (int n = 0; n < 4; n++)
                acc[mh * 4 + m][n] = __builtin_amdgcn_mfma_f32_16x16x32_bf16(af[m], bfr[n], acc[mh * 4 + m][n], 0, 0, 0);
        __builtin_amdgcn_s_setprio(0);
        if (wait == 4)      { __builtin_amdgcn_s_waitcnt(0x0F74); __builtin_amdgcn_sched_barrier(0); }
        else if (wait == 0) { __builtin_amdgcn_s_waitcnt(0x0F70); __builtin_amdgcn_sched_barrier(0); }
        if (bar) { __builtin_amdgcn_s_barrier(); __builtin_amdgcn_sched_barrier(0); }
    };

    // prologue: stage all 4 half-tiles of tile 0; certify the first two (vmcnt(4))
    stage(0, 0); stage(0, 1); stage(0, 2); stage(0, 3);
    __builtin_amdgcn_s_waitcnt(0x0F74);
    __builtin_amdgcn_sched_barrier(0);
    __builtin_amdgcn_s_barrier();
    __builtin_amdgcn_sched_barrier(0);

    for (int t = 0; t < nk - 1; ++t) {
        phase(t, 0, 0, 0, -1, false);
        phase(t, 1, 0, 1,  4, true);    // certify A-ks1,B-ks1 of tile t
        phase(t, 0, 1, 2, -1, false);
        phase(t, 1, 1, 3,  4, true);    // certify A-ks0,B-ks0 of tile t+1
    }
    {
        int t = nk - 1;
        phase(t, 0, 0, -1, -1, false);
        phase(t, 1, 0, -1,  0, true);   // drain: certify A-ks1,B-ks1 of the last tile
        phase(t, 0, 1, -1, -1, false);
        phase(t, 1, 1, -1, -1, false);
    }

    #pragma unroll
    for (int mf = 0; mf < 8; mf++)
      #pragma unroll
      for (int n = 0; n < 4; n++)
        #pragma unroll
        for (int r = 0; r < 4; r++) {
            size_t row = m0 + wm * 128 + mf * 16 + quad * 4 + r;
            size_t col = n0 + wn * 64 + n * 16 + ln;
            float v = acc[mf][n][r];
            if (OUT_F32) ((float*)Cout)[row * N + col] = v;
            else         ((u16*)Cout)[row * N + col] = f2bf(v);
        }
}

// ---------------- flash attention v3: shared K/V tiles, 128-query blocks ----------------
// Block = 128 queries x (b,h), 4 waves each owning 32 queries. All waves iterate the SAME key
// tiles; K/V staged in LDS once per block via global_load_lds (16 x 1KB DMA, 4 per wave),
// double-buffered with one-tile-ahead prefetch. Raw s_barrier + counted vmcnt(4).
// LDS layout = read order: every ds_read_b128 is lane-linear over a contiguous 1KB group =>
// conflict-free. In-register softmax via sigma-permuted K rows + cvt_pk P-pack:
//   sigma(m) = (m&3) + 4*bit3(m) + 8*bit2(m) + 16*bit4(m)
//   S^T reg r holds key s0 + (r&3) + 4*((r>>2)&1) + 8*hi + 16*(r>>3), col q = ln.
__global__ __launch_bounds__(256, 2) void attn_kernel(const u16* __restrict__ QKV,
                                                      const u16* __restrict__ Vt,
                                                      u16* __restrict__ Enc) {
    // buf[2] x { K: 8KB (groups ks=0..7, 1KB each) | V: 8KB (groups g=dt*2+half) } = 32KB
    __shared__ alignas(16) u16 pool[2 * 8192];

    int tid = threadIdx.x;
    int w = tid >> 6, lane = tid & 63, hi = lane >> 5, ln = lane & 31;
    int hi8 = hi * 8;

    int qb = (15 - (int)blockIdx.x) * 128;      // long blocks first
    int bh = blockIdx.y;
    int b = bh >> 4, h = bh & 15, kh = h >> 2;
    int qw = qb + w * 32;                        // this wave's query base

    // Q B-frag [n=q=ln][k=hi*8 + ks*16 + j]
    short8 qf[8];
    {
        const u16* qptr = QKV + (size_t)(b * TT + qw + ln) * SQKV + h * HD + hi8;
        #pragma unroll
        for (int ks = 0; ks < 8; ks++) qf[ks] = *(const short8*)(qptr + ks * 16);
    }

    // ---- DMA source setup: wave w issues groups [w*4, w*4+4) of {K0..7, V0..7} ----
    int sig = (ln & 3) + (((ln >> 3) & 1) << 2) + (((ln >> 2) & 1) << 3) + ((ln >> 4) << 4);
    bool isK = (w < 2);
    const u16* dsrc[4];
    int ldst[4];                                 // u16 offset within a 16KB buffer
    #pragma unroll
    for (int i = 0; i < 4; i++) {
        if (isK) {
            int ks = w * 4 + i;
            dsrc[i] = QKV + (size_t)(b * TT + sig) * SQKV + 2048 + kh * HD + ks * 16 + hi8;
            ldst[i] = ks * 512;
        } else {
            int g = (w - 2) * 4 + i;
            dsrc[i] = Vt + (size_t)((b * NKV + kh) * HD + (g >> 1) * 32 + ln) * TT + (g & 1) * 16 + hi8;
            ldst[i] = 4096 + g * 512;
        }
    }
    size_t addmul = isK ? (size_t)SQKV : (size_t)1;

    floatx16 O0 = {}, O1 = {}, O2 = {}, O3 = {};   // O^T d-tiles: D[m=d][n=q]
    float lacc = 0.0f;

    int S_LO = qb - WINDOW; if (S_LO < 0) S_LO = 0;
    int nt = (qb + 128 - S_LO) >> 5;

    auto issue = [&](int t) {
        int s0 = S_LO + t * 32;
        u16* base = pool + (t & 1) * 8192;
        size_t add = (size_t)s0 * addmul;
        #pragma unroll
        for (int i = 0; i < 4; i++)
            __builtin_amdgcn_global_load_lds((gas_ptr)(dsrc[i] + add), (las_ptr)(base + ldst[i]), 16, 0, 0);
    };

    issue(0);
    for (int t = 0; t < nt; ++t) {
        // barrier A: all waves done reading buf[(t+1)&1] (= tile t-1's buffer)
        __builtin_amdgcn_sched_barrier(0);
        __builtin_amdgcn_s_barrier();
        __builtin_amdgcn_sched_barrier(0);
        if (t + 1 < nt) {
            issue(t + 1);
            __builtin_amdgcn_sched_barrier(0);
            __builtin_amdgcn_s_waitcnt(0x0F74);   // vmcnt(4): own tile-t DMAs landed, t+1 in flight
        } else {
            __builtin_amdgcn_s_waitcnt(0x0F70);   // vmcnt(0): last tile, drain all
        }
        __builtin_amdgcn_sched_barrier(0);
        __builtin_amdgcn_s_barrier();             // barrier B: ALL waves' tile-t data in LDS
        __builtin_amdgcn_sched_barrier(0);

        int s0 = S_LO + t * 32;
        if (s0 > qw + 31 || s0 + 31 < qw - WINDOW) continue;   // tile outside this wave's window

        const u16* Kb = pool + (t & 1) * 8192;
        const u16* Vb = Kb + 4096;

        // ---- S^T = K Q^T (rows = sigma-permuted keys, cols = q) ----
        floatx16 S = {};
        #pragma unroll
        for (int ks = 0; ks < 8; ks++) {
            short8 kf = *(const short8*)(Kb + ks * 512 + lane * 8);   // lane-linear: conflict-free
            S = __builtin_amdgcn_mfma_f32_32x32x16_bf16(kf, qf[ks], S, 0, 0, 0);
        }

        // ---- softcap + exp (+ mask only on edge tiles), in place ----
        bool full = (s0 + 31 <= qw) && (s0 >= qw + 31 - WINDOW);
        if (full) {
            #pragma unroll
            for (int r = 0; r < 16; r++) S[r] = softcap_exp(S[r]);
        } else {
            int tq = qw + ln;
            #pragma unroll
            for (int r = 0; r < 16; r++) {
                int s = s0 + (r & 3) + (((r >> 2) & 1) << 2) + hi8 + ((r >> 3) << 4);
                bool good = (s <= tq) && (s >= tq - WINDOW);
                S[r] = good ? softcap_exp(S[r]) : 0.0f;
            }
        }

        // ---- own-half l accumulation (tree) ----
        lacc += ((((S[0] + S[1]) + (S[2] + S[3])) + ((S[4] + S[5]) + (S[6] + S[7])))
               + (((S[8] + S[9]) + (S[10] + S[11])) + ((S[12] + S[13]) + (S[14] + S[15]))));

        // ---- pack P -> bf16 B-frags (already frag-ordered thanks to sigma) ----
        u32 w0a = cvt_pk_bf16(S[0],  S[1]),  w0b = cvt_pk_bf16(S[2],  S[3]);
        u32 w0c = cvt_pk_bf16(S[4],  S[5]),  w0d = cvt_pk_bf16(S[6],  S[7]);
        u32 w1a = cvt_pk_bf16(S[8],  S[9]),  w1b = cvt_pk_bf16(S[10], S[11]);
        u32 w1c = cvt_pk_bf16(S[12], S[13]), w1d = cvt_pk_bf16(S[14], S[15]);
        typedef __attribute__((ext_vector_type(4))) unsigned int u32x4t;
        u32x4t pw0 = { w0a, w0b, w0c, w0d };
        u32x4t pw1 = { w1a, w1b, w1c, w1d };
        short8 pf0 = __builtin_bit_cast(short8, pw0);
        short8 pf1 = __builtin_bit_cast(short8, pw1);

        // ---- O^T += V^T P^T (V frags lane-linear 1KB reads: conflict-free) ----
        #pragma unroll
        for (int dt = 0; dt < 4; dt++) {
            short8 vf0 = *(const short8*)(Vb + (dt * 2 + 0) * 512 + lane * 8);
            short8 vf1 = *(const short8*)(Vb + (dt * 2 + 1) * 512 + lane * 8);
            floatx16* Od = (dt == 0) ? &O0 : (dt == 1) ? &O1 : (dt == 2) ? &O2 : &O3;
            *Od = __builtin_amdgcn_mfma_f32_32x32x16_bf16(vf0, pf0, *Od, 0, 0, 0);
            *Od = __builtin_amdgcn_mfma_f32_32x32x16_bf16(vf1, pf1, *Od, 0, 0, 0);
        }
    }

    __syncthreads();   // drain everything; staging LDS is now free for the epilogue

    // ---- epilogue: normalize, transpose O^T -> O via wave-private 2KB LDS bounce ----
    lacc += __shfl_xor(lacc, 32);                  // fold the other key-half (same q on lane^32)
    float inv = __builtin_amdgcn_rcpf(lacc);
    u16* ep = pool + w * 1024;                     // [32 q][32 d] bf16 per dt pass
    const floatx16* Os[4] = { &O0, &O1, &O2, &O3 };
    #pragma unroll
    for (int dt = 0; dt < 4; dt++) {
        #pragma unroll
        for (int g = 0; g < 4; g++) {
            // reg r=g*4+i -> d_local = i + 8g + 4hi, col q=ln
            float a0 = (*Os[dt])[g * 4 + 0] * inv, a1 = (*Os[dt])[g * 4 + 1] * inv;
            float a2 = (*Os[dt])[g * 4 + 2] * inv, a3 = (*Os[dt])[g * 4 + 3] * inv;
            uint2v pk;
            pk[0] = cvt_pk_bf16(a0, a1);
            pk[1] = cvt_pk_bf16(a2, a3);
            *(uint2v*)(ep + ln * 32 + g * 8 + hi * 4) = pk;   // same-wave DS pipe is in-order
        }
        ushort8 r0 = *(const ushort8*)(ep + ln * 32 + hi * 16);
        ushort8 r1 = *(const ushort8*)(ep + ln * 32 + hi * 16 + 8);
        u16* dst = Enc + (size_t)(b * TT + qw + ln) * (NH * HD) + h * HD + dt * 32 + hi * 16;
        *(ushort8*)dst = r0;
        *(ushort8*)(dst + 8) = r1;
    }
}

extern "C" void kernel_launch(void* const* d_in, const int* in_sizes, int n_in,
                              void* d_out, int out_size, void* d_ws, size_t ws_size,
                              hipStream_t stream) {
    const float* x  = (const float*)d_in[0];
    const float* wq = (const float*)d_in[1];
    const float* wk = (const float*)d_in[2];
    const float* wv = (const float*)d_in[3];
    const float* wo = (const float*)d_in[4];
    float* out = (float*)d_out;

    char* ws = (char*)d_ws;
    size_t off = 0;
    auto alloc = [&](size_t bytes) -> void* {
        void* p = ws + off;
        off += (bytes + 255) & ~(size_t)255;
        return p;
    };
    u16* xb    = (u16*)alloc((size_t)BT * CC * 2);
    u16* wqkvT = (u16*)alloc((size_t)SQKV * CC * 2);   // rows: Wq^T 0-2047, Wk^T 2048-2559, Wv^T 2560-3071
    u16* woT   = (u16*)alloc((size_t)CC * CC * 2);
    u16* QKVb  = (u16*)alloc((size_t)BT * SQKV * 2);   // [4096][3072]
    u16* VtT   = (u16*)alloc((size_t)BT * NKV * HD * 2); // [B][NKV][HD][T]
    u16* Enc   = (u16*)alloc((size_t)BT * NH * HD * 2);

    // 1) casts / weight transposes
    cast_bf16_kernel<<<(BT * CC / 4 + 255) / 256, 256, 0, stream>>>(x, xb, BT * CC / 4);
    dim3 tb(32, 8);
    transpose_cast_f32_kernel<<<dim3(CC / 32, CC / 32), tb, 0, stream>>>(wq, wqkvT, CC, CC);
    transpose_cast_f32_kernel<<<dim3(NKV * HD / 32, CC / 32), tb, 0, stream>>>(wk, wqkvT + (size_t)2048 * CC, CC, NKV * HD);
    transpose_cast_f32_kernel<<<dim3(NKV * HD / 32, CC / 32), tb, 0, stream>>>(wv, wqkvT + (size_t)2560 * CC, CC, NKV * HD);
    transpose_cast_f32_kernel<<<dim3(CC / 32, CC / 32), tb, 0, stream>>>(wo, woT, CC, CC);

    // 2) merged QKV projection (N=3072): 256x256 8-phase template (192 blocks)
    gemm256sq_kernel<false><<<dim3(SQKV / 256, BT / 256), 512, 0, stream>>>(xb, wqkvT, QKVb, BT, SQKV, CC);

    // 3) RoPE (scale folded into Q); K at col offset 2048, row stride 3072
    rope_kernel<<<BT * NH, HD, 0, stream>>>(QKVb, NH, SQKV, 0.08838834764831845f);
    rope_kernel<<<BT * NKV, HD, 0, stream>>>(QKVb + 2048, NKV, SQKV, 1.0f);

    // 4) V -> V^T per batch: QKVb cols 2560.. -> [512][T]
    transpose_bf16_kernel<<<dim3(TT / 32, NKV * HD / 32, BB), tb, 0, stream>>>(
        QKVb, VtT, TT, NKV * HD, SQKV, 2560,
        (size_t)TT * SQKV, (size_t)NKV * HD * TT);

    // 5) flash attention: 512 blocks (16 query-blocks x 32 bh), shared K/V tiles per block
    attn_kernel<<<dim3(16, 32), 256, 0, stream>>>(QKVb, VtT, Enc);

    // 6) output projection (fp32 out): proven m97-style 128^2 GEMM (512 blocks)
    gemm128_kernel<true><<<dim3(CC / 128, BT / 128), 256, 0, stream>>>(Enc, woT, out, BT, CC, CC);
}

// Round 7
// 315.412 us; speedup vs baseline: 1.1516x; 1.0465x over previous
//
#include <hip/hip_runtime.h>
#include <hip/hip_bf16.h>
#include <math.h>

#define BB 2
#define TT 2048
#define CC 2048
#define NH 16
#define NKV 4
#define HD 128
#define BT (BB*TT)
#define WINDOW 1024
#define SQKV 3072   // QKV buffer row stride: Q cols 0-2047, K 2048-2559 (V lives only in Vt)

typedef unsigned short u16;
typedef unsigned int u32;
typedef __attribute__((ext_vector_type(8))) short short8;      // 8 bf16 = 4 VGPRs (MFMA A/B frag)
typedef __attribute__((ext_vector_type(8))) unsigned short ushort8;
typedef __attribute__((ext_vector_type(4))) unsigned short ushort4v;
typedef __attribute__((ext_vector_type(2))) unsigned int uint2v;
typedef __attribute__((ext_vector_type(4))) float floatx4;     // 16x16 MFMA C/D frag
typedef __attribute__((ext_vector_type(16))) float floatx16;   // 32x32 MFMA C/D frag

typedef const __attribute__((address_space(1))) u32* gas_ptr;
typedef __attribute__((address_space(3))) u32* las_ptr;

static __device__ __forceinline__ u16 f2bf(float f) {
    unsigned u = __builtin_bit_cast(unsigned, f);
    return (u16)((u + 0x7fffu + ((u >> 16) & 1u)) >> 16);   // RNE
}
static __device__ __forceinline__ float bf2f(u16 v) {
    unsigned u = ((unsigned)v) << 16;
    return __builtin_bit_cast(float, u);
}

// packed f32x2 -> bf16x2 (RNE), low half = lo, high half = hi
static __device__ __forceinline__ u32 cvt_pk_bf16(float lo, float hi) {
    u32 r;
    asm("v_cvt_pk_bf16_f32 %0, %1, %2" : "=v"(r) : "v"(lo), "v"(hi));
    return r;
}

// softcap+exp: exp(50*tanh(s/50)) = exp2( t*(c0 + c1 t^2 + c2 t^4) ), t=s/50 clamped to [-1,1].
static __device__ __forceinline__ float softcap_exp(float s) {
    float t = s * 0.02f;
    t = fmaxf(-1.0f, fminf(1.0f, t));     // v_med3
    float t2 = t * t;
    float e = t * fmaf(t2, fmaf(t2, 9.617967f, -24.044917f), 72.134752f);
    return __builtin_amdgcn_exp2f(e);
}

// ---------------- elementwise cast fp32 -> bf16 ----------------
__global__ void cast_bf16_kernel(const float* __restrict__ in, u16* __restrict__ out, int n4) {
    int i = blockIdx.x * blockDim.x + threadIdx.x;
    if (i >= n4) return;
    floatx4 v = *(const floatx4*)(in + (size_t)i * 4);
    ushort4v o;
    o[0] = f2bf(v[0]); o[1] = f2bf(v[1]); o[2] = f2bf(v[2]); o[3] = f2bf(v[3]);
    *(ushort4v*)(out + (size_t)i * 4) = o;
}

// ---------------- transpose + cast fp32 [R][Cc] -> bf16 [Cc][R] ----------------
__global__ void transpose_cast_f32_kernel(const float* __restrict__ in, u16* __restrict__ out,
                                          int R, int Cc) {
    __shared__ u16 tile[32][33];
    int c0 = blockIdx.x * 32, r0 = blockIdx.y * 32;
    int tx = threadIdx.x, ty = threadIdx.y;   // block (32, 8)
    #pragma unroll
    for (int i = 0; i < 4; i++) {
        int r = r0 + ty + i * 8;
        tile[ty + i * 8][tx] = f2bf(in[(size_t)r * Cc + c0 + tx]);
    }
    __syncthreads();
    #pragma unroll
    for (int i = 0; i < 4; i++) {
        int c = c0 + ty + i * 8;
        out[(size_t)c * R + r0 + tx] = tile[tx][ty + i * 8];
    }
}

// ---------------- RoPE trig table: tab[t][j] = {cos, sin}(t * 10000^(-j/64)) ----------------
// Bit-identical arithmetic to the old per-element rope (exp2f + sincosf), evaluated once per (t,j)
// instead of once per (b,t,h,d): 131K trig calls instead of 10.5M.
__global__ void trig_table_kernel(float* __restrict__ tab) {
    int t = blockIdx.x, j = threadIdx.x;          // grid TT x 64
    float inv = exp2f(-0.20762050593046f * (float)j);   // 10000^(-j/64)
    float s, c;
    sincosf((float)t * inv, &s, &c);
    float* p = tab + (t * 64 + j) * 2;
    p[0] = c; p[1] = s;
}

// ---------------- RoPE (vectorized pairs): thread owns (d=j0..j0+3, d+64) of one head ----------------
// block = H*16 threads (16 threads/head, 4 j each); grid = BT rows. In-place, no sync needed
// (each thread owns its pair exclusively). o_lo = x_lo*c - x_hi*s ; o_hi = x_hi*c + x_lo*s.
__global__ void rope_fast_kernel(u16* __restrict__ buf, const float* __restrict__ tab,
                                 int rowStride, float scale) {
    int bt = blockIdx.x;
    int t = bt & (TT - 1);
    int tid = threadIdx.x;
    int h = tid >> 4;
    int j0 = (tid & 15) * 4;
    u16* p = buf + (size_t)bt * rowStride + h * HD + j0;
    ushort4v lo = *(const ushort4v*)(p);
    ushort4v hi = *(const ushort4v*)(p + 64);
    const float* tb = tab + (t * 64 + j0) * 2;    // 8 contiguous floats: c0,s0,c1,s1,...
    ushort4v olo, ohi;
    #pragma unroll
    for (int i = 0; i < 4; i++) {
        float c = tb[2 * i], s = tb[2 * i + 1];
        float x1 = bf2f(lo[i]), x2 = bf2f(hi[i]);
        olo[i] = f2bf((x1 * c - x2 * s) * scale);
        ohi[i] = f2bf((x2 * c + x1 * s) * scale);
    }
    *(ushort4v*)(p) = olo;
    *(ushort4v*)(p + 64) = ohi;
}

// ---------------- m97-style GEMM: C[M][N] = A[M][K] * Bt[N][K]^T (bf16 in, fp32 acc) ----------------
// Proven at ~700 TF on this workload (R2). OMODE: 0 = bf16 out, 1 = f32 out,
// 2 = QKV mode: cols < 2560 -> bf16 to Cout; V cols (>=2560, block-uniform) -> Vt TRANSPOSED
//     (Vt[b][c][t], thread's 4 acc rows = 4 consecutive tokens = one ushort4 store).
template <int OMODE>
__global__ __launch_bounds__(256) void gemm128_kernel(const u16* __restrict__ A,
                                                      const u16* __restrict__ Bt,
                                                      void* __restrict__ Cout,
                                                      u16* __restrict__ Vt,
                                                      int M, int N, int K) {
    __shared__ alignas(16) u16 As[128 * 32];   // row-major [128][32], NO padding (lds-dma layout)
    __shared__ alignas(16) u16 Bs[128 * 32];
    int tid = threadIdx.x;
    int w = tid >> 6, lane = tid & 63, quad = lane >> 4, ln = lane & 15;
    int m0 = blockIdx.y * 128;
    int n0 = blockIdx.x * 128;
    int wm = (w >> 1) * 64;
    int wn = (w & 1) * 64;

    int o0 = (w * 2) * 1024 + lane * 16;
    int row0 = o0 >> 6, kc0 = (o0 & 63) >> 4;
    int o1 = o0 + 1024;
    int row1 = o1 >> 6, kc1 = (o1 & 63) >> 4;
    const u16* gA0 = A  + (size_t)(m0 + row0) * K + kc0 * 8;
    const u16* gA1 = A  + (size_t)(m0 + row1) * K + kc1 * 8;
    const u16* gB0 = Bt + (size_t)(n0 + row0) * K + kc0 * 8;
    const u16* gB1 = Bt + (size_t)(n0 + row1) * K + kc1 * 8;
    u16* lA0 = As + (w * 2) * 512;
    u16* lA1 = As + (w * 2 + 1) * 512;
    u16* lB0 = Bs + (w * 2) * 512;
    u16* lB1 = Bs + (w * 2 + 1) * 512;

    floatx4 acc[4][4] = {};

    for (int k0 = 0; k0 < K; k0 += 32) {
        __syncthreads();
        __builtin_amdgcn_global_load_lds((gas_ptr)(gA0 + k0), (las_ptr)lA0, 16, 0, 0);
        __builtin_amdgcn_global_load_lds((gas_ptr)(gA1 + k0), (las_ptr)lA1, 16, 0, 0);
        __builtin_amdgcn_global_load_lds((gas_ptr)(gB0 + k0), (las_ptr)lB0, 16, 0, 0);
        __builtin_amdgcn_global_load_lds((gas_ptr)(gB1 + k0), (las_ptr)lB1, 16, 0, 0);
        __syncthreads();

        short8 af[4], bf[4];
        #pragma unroll
        for (int mt = 0; mt < 4; mt++)
            af[mt] = *(const short8*)(As + (wm + mt * 16 + ln) * 32 + quad * 8);
        #pragma unroll
        for (int nt = 0; nt < 4; nt++)
            bf[nt] = *(const short8*)(Bs + (wn + nt * 16 + ln) * 32 + quad * 8);
        #pragma unroll
        for (int mt = 0; mt < 4; mt++)
            #pragma unroll
            for (int nt = 0; nt < 4; nt++)
                acc[mt][nt] = __builtin_amdgcn_mfma_f32_16x16x32_bf16(af[mt], bf[nt], acc[mt][nt], 0, 0, 0);
    }

    if (OMODE == 2 && n0 >= 2560) {
        // whole block is V (2560 = 20*128): write transposed to Vt[b][c][t]
        int b = m0 >> 11;                          // TT = 2048, 128 | 2048 => uniform per block
        int tb = (m0 & (TT - 1)) + wm;
        #pragma unroll
        for (int mt = 0; mt < 4; mt++)
          #pragma unroll
          for (int nt = 0; nt < 4; nt++) {
              int c = n0 + wn + nt * 16 + ln - 2560;
              int t0 = tb + mt * 16 + quad * 4;
              ushort4v o;
              #pragma unroll
              for (int r = 0; r < 4; r++) o[r] = f2bf(acc[mt][nt][r]);
              *(ushort4v*)(Vt + (size_t)b * (NKV * HD) * TT + (size_t)c * TT + t0) = o;
          }
    } else {
        #pragma unroll
        for (int mt = 0; mt < 4; mt++)
          #pragma unroll
          for (int nt = 0; nt < 4; nt++)
            #pragma unroll
            for (int r = 0; r < 4; r++) {
                size_t row = m0 + wm + mt * 16 + quad * 4 + r;
                size_t col = n0 + wn + nt * 16 + ln;
                float v = acc[mt][nt][r];
                if (OMODE == 1) ((float*)Cout)[row * N + col] = v;
                else            ((u16*)Cout)[row * N + col] = f2bf(v);
            }
    }
}

// ---------------- flash attention v3: shared K/V tiles, 128-query blocks ----------------
// Block = 128 queries x (b,h), 4 waves each owning 32 queries. All waves iterate the SAME key
// tiles; K/V staged in LDS once per block via global_load_lds (16 x 1KB DMA, 4 per wave),
// double-buffered with one-tile-ahead prefetch. Raw s_barrier + counted vmcnt(4).
// LDS layout = read order: every ds_read_b128 is lane-linear over a contiguous 1KB group =>
// conflict-free. In-register softmax via sigma-permuted K rows + cvt_pk P-pack:
//   sigma(m) = (m&3) + 4*bit3(m) + 8*bit2(m) + 16*bit4(m)
//   S^T reg r holds key s0 + (r&3) + 4*((r>>2)&1) + 8*hi + 16*(r>>3), col q = ln.
__global__ __launch_bounds__(256, 2) void attn_kernel(const u16* __restrict__ QKV,
                                                      const u16* __restrict__ Vt,
                                                      u16* __restrict__ Enc) {
    // buf[2] x { K: 8KB (groups ks=0..7, 1KB each) | V: 8KB (groups g=dt*2+half) } = 32KB
    __shared__ alignas(16) u16 pool[2 * 8192];

    int tid = threadIdx.x;
    int w = tid >> 6, lane = tid & 63, hi = lane >> 5, ln = lane & 31;
    int hi8 = hi * 8;

    int qb = (15 - (int)blockIdx.x) * 128;      // long blocks first
    int bh = blockIdx.y;
    int b = bh >> 4, h = bh & 15, kh = h >> 2;
    int qw = qb + w * 32;                        // this wave's query base

    // Q B-frag [n=q=ln][k=hi*8 + ks*16 + j]
    short8 qf[8];
    {
        const u16* qptr = QKV + (size_t)(b * TT + qw + ln) * SQKV + h * HD + hi8;
        #pragma unroll
        for (int ks = 0; ks < 8; ks++) qf[ks] = *(const short8*)(qptr + ks * 16);
    }

    // ---- DMA source setup: wave w issues groups [w*4, w*4+4) of {K0..7, V0..7} ----
    int sig = (ln & 3) + (((ln >> 3) & 1) << 2) + (((ln >> 2) & 1) << 3) + ((ln >> 4) << 4);
    bool isK = (w < 2);
    const u16* dsrc[4];
    int ldst[4];                                 // u16 offset within a 16KB buffer
    #pragma unroll
    for (int i = 0; i < 4; i++) {
        if (isK) {
            int ks = w * 4 + i;
            dsrc[i] = QKV + (size_t)(b * TT + sig) * SQKV + 2048 + kh * HD + ks * 16 + hi8;
            ldst[i] = ks * 512;
        } else {
            int g = (w - 2) * 4 + i;
            dsrc[i] = Vt + (size_t)((b * NKV + kh) * HD + (g >> 1) * 32 + ln) * TT + (g & 1) * 16 + hi8;
            ldst[i] = 4096 + g * 512;
        }
    }
    size_t addmul = isK ? (size_t)SQKV : (size_t)1;

    floatx16 O0 = {}, O1 = {}, O2 = {}, O3 = {};   // O^T d-tiles: D[m=d][n=q]
    float lacc = 0.0f;

    int S_LO = qb - WINDOW; if (S_LO < 0) S_LO = 0;
    int nt = (qb + 128 - S_LO) >> 5;

    auto issue = [&](int t) {
        int s0 = S_LO + t * 32;
        u16* base = pool + (t & 1) * 8192;
        size_t add = (size_t)s0 * addmul;
        #pragma unroll
        for (int i = 0; i < 4; i++)
            __builtin_amdgcn_global_load_lds((gas_ptr)(dsrc[i] + add), (las_ptr)(base + ldst[i]), 16, 0, 0);
    };

    issue(0);
    for (int t = 0; t < nt; ++t) {
        // barrier A: all waves done reading buf[(t+1)&1] (= tile t-1's buffer)
        __builtin_amdgcn_sched_barrier(0);
        __builtin_amdgcn_s_barrier();
        __builtin_amdgcn_sched_barrier(0);
        if (t + 1 < nt) {
            issue(t + 1);
            __builtin_amdgcn_sched_barrier(0);
            __builtin_amdgcn_s_waitcnt(0x0F74);   // vmcnt(4): own tile-t DMAs landed, t+1 in flight
        } else {
            __builtin_amdgcn_s_waitcnt(0x0F70);   // vmcnt(0): last tile, drain all
        }
        __builtin_amdgcn_sched_barrier(0);
        __builtin_amdgcn_s_barrier();             // barrier B: ALL waves' tile-t data in LDS
        __builtin_amdgcn_sched_barrier(0);

        int s0 = S_LO + t * 32;
        if (s0 > qw + 31 || s0 + 31 < qw - WINDOW) continue;   // tile outside this wave's window

        const u16* Kb = pool + (t & 1) * 8192;
        const u16* Vb = Kb + 4096;

        // ---- S^T = K Q^T (rows = sigma-permuted keys, cols = q) ----
        floatx16 S = {};
        #pragma unroll
        for (int ks = 0; ks < 8; ks++) {
            short8 kf = *(const short8*)(Kb + ks * 512 + lane * 8);   // lane-linear: conflict-free
            S = __builtin_amdgcn_mfma_f32_32x32x16_bf16(kf, qf[ks], S, 0, 0, 0);
        }

        // ---- softcap + exp (+ mask only on edge tiles), in place ----
        bool full = (s0 + 31 <= qw) && (s0 >= qw + 31 - WINDOW);
        if (full) {
            #pragma unroll
            for (int r = 0; r < 16; r++) S[r] = softcap_exp(S[r]);
        } else {
            int tq = qw + ln;
            #pragma unroll
            for (int r = 0; r < 16; r++) {
                int s = s0 + (r & 3) + (((r >> 2) & 1) << 2) + hi8 + ((r >> 3) << 4);
                bool good = (s <= tq) && (s >= tq - WINDOW);
                S[r] = good ? softcap_exp(S[r]) : 0.0f;
            }
        }

        // ---- own-half l accumulation (tree) ----
        lacc += ((((S[0] + S[1]) + (S[2] + S[3])) + ((S[4] + S[5]) + (S[6] + S[7])))
               + (((S[8] + S[9]) + (S[10] + S[11])) + ((S[12] + S[13]) + (S[14] + S[15]))));

        // ---- pack P -> bf16 B-frags (already frag-ordered thanks to sigma) ----
        u32 w0a = cvt_pk_bf16(S[0],  S[1]),  w0b = cvt_pk_bf16(S[2],  S[3]);
        u32 w0c = cvt_pk_bf16(S[4],  S[5]),  w0d = cvt_pk_bf16(S[6],  S[7]);
        u32 w1a = cvt_pk_bf16(S[8],  S[9]),  w1b = cvt_pk_bf16(S[10], S[11]);
        u32 w1c = cvt_pk_bf16(S[12], S[13]), w1d = cvt_pk_bf16(S[14], S[15]);
        typedef __attribute__((ext_vector_type(4))) unsigned int u32x4t;
        u32x4t pw0 = { w0a, w0b, w0c, w0d };
        u32x4t pw1 = { w1a, w1b, w1c, w1d };
        short8 pf0 = __builtin_bit_cast(short8, pw0);
        short8 pf1 = __builtin_bit_cast(short8, pw1);

        // ---- O^T += V^T P^T (V frags lane-linear 1KB reads: conflict-free) ----
        #pragma unroll
        for (int dt = 0; dt < 4; dt++) {
            short8 vf0 = *(const short8*)(Vb + (dt * 2 + 0) * 512 + lane * 8);
            short8 vf1 = *(const short8*)(Vb + (dt * 2 + 1) * 512 + lane * 8);
            floatx16* Od = (dt == 0) ? &O0 : (dt == 1) ? &O1 : (dt == 2) ? &O2 : &O3;
            *Od = __builtin_amdgcn_mfma_f32_32x32x16_bf16(vf0, pf0, *Od, 0, 0, 0);
            *Od = __builtin_amdgcn_mfma_f32_32x32x16_bf16(vf1, pf1, *Od, 0, 0, 0);
        }
    }

    __syncthreads();   // drain everything; staging LDS is now free for the epilogue

    // ---- epilogue: normalize, transpose O^T -> O via wave-private 2KB LDS bounce ----
    lacc += __shfl_xor(lacc, 32);                  // fold the other key-half (same q on lane^32)
    float inv = __builtin_amdgcn_rcpf(lacc);
    u16* ep = pool + w * 1024;                     // [32 q][32 d] bf16 per dt pass
    const floatx16* Os[4] = { &O0, &O1, &O2, &O3 };
    #pragma unroll
    for (int dt = 0; dt < 4; dt++) {
        #pragma unroll
        for (int g = 0; g < 4; g++) {
            // reg r=g*4+i -> d_local = i + 8g + 4hi, col q=ln
            float a0 = (*Os[dt])[g * 4 + 0] * inv, a1 = (*Os[dt])[g * 4 + 1] * inv;
            float a2 = (*Os[dt])[g * 4 + 2] * inv, a3 = (*Os[dt])[g * 4 + 3] * inv;
            uint2v pk;
            pk[0] = cvt_pk_bf16(a0, a1);
            pk[1] = cvt_pk_bf16(a2, a3);
            *(uint2v*)(ep + ln * 32 + g * 8 + hi * 4) = pk;   // same-wave DS pipe is in-order
        }
        ushort8 r0 = *(const ushort8*)(ep + ln * 32 + hi * 16);
        ushort8 r1 = *(const ushort8*)(ep + ln * 32 + hi * 16 + 8);
        u16* dst = Enc + (size_t)(b * TT + qw + ln) * (NH * HD) + h * HD + dt * 32 + hi * 16;
        *(ushort8*)dst = r0;
        *(ushort8*)(dst + 8) = r1;
    }
}

extern "C" void kernel_launch(void* const* d_in, const int* in_sizes, int n_in,
                              void* d_out, int out_size, void* d_ws, size_t ws_size,
                              hipStream_t stream) {
    const float* x  = (const float*)d_in[0];
    const float* wq = (const float*)d_in[1];
    const float* wk = (const float*)d_in[2];
    const float* wv = (const float*)d_in[3];
    const float* wo = (const float*)d_in[4];
    float* out = (float*)d_out;

    char* ws = (char*)d_ws;
    size_t off = 0;
    auto alloc = [&](size_t bytes) -> void* {
        void* p = ws + off;
        off += (bytes + 255) & ~(size_t)255;
        return p;
    };
    u16* xb    = (u16*)alloc((size_t)BT * CC * 2);
    u16* wqkvT = (u16*)alloc((size_t)SQKV * CC * 2);   // rows: Wq^T 0-2047, Wk^T 2048-2559, Wv^T 2560-3071
    u16* woT   = (u16*)alloc((size_t)CC * CC * 2);
    u16* QKVb  = (u16*)alloc((size_t)BT * SQKV * 2);   // [4096][3072] (V region unused)
    u16* VtT   = (u16*)alloc((size_t)BT * NKV * HD * 2); // [B][NKV*HD][T]
    u16* Enc   = (u16*)alloc((size_t)BT * NH * HD * 2);
    float* trig = (float*)alloc((size_t)TT * 64 * 2 * 4); // [T][64][{cos,sin}]

    // 0) RoPE trig table (input-independent)
    trig_table_kernel<<<TT, 64, 0, stream>>>(trig);

    // 1) casts / weight transposes
    cast_bf16_kernel<<<(BT * CC / 4 + 255) / 256, 256, 0, stream>>>(x, xb, BT * CC / 4);
    dim3 tb(32, 8);
    transpose_cast_f32_kernel<<<dim3(CC / 32, CC / 32), tb, 0, stream>>>(wq, wqkvT, CC, CC);
    transpose_cast_f32_kernel<<<dim3(NKV * HD / 32, CC / 32), tb, 0, stream>>>(wk, wqkvT + (size_t)2048 * CC, CC, NKV * HD);
    transpose_cast_f32_kernel<<<dim3(NKV * HD / 32, CC / 32), tb, 0, stream>>>(wv, wqkvT + (size_t)2560 * CC, CC, NKV * HD);
    transpose_cast_f32_kernel<<<dim3(CC / 32, CC / 32), tb, 0, stream>>>(wo, woT, CC, CC);

    // 2) merged QKV projection (N=3072, 768 blocks); V columns written directly to VtT transposed
    gemm128_kernel<2><<<dim3(SQKV / 128, BT / 128), 256, 0, stream>>>(xb, wqkvT, QKVb, VtT, BT, SQKV, CC);

    // 3) RoPE via table (scale folded into Q); K at col offset 2048, row stride 3072
    rope_fast_kernel<<<BT, NH * 16, 0, stream>>>(QKVb, trig, SQKV, 0.08838834764831845f);
    rope_fast_kernel<<<BT, NKV * 16, 0, stream>>>(QKVb + 2048, trig, SQKV, 1.0f);

    // 4) flash attention: 512 blocks (16 query-blocks x 32 bh), shared K/V tiles per block
    attn_kernel<<<dim3(16, 32), 256, 0, stream>>>(QKVb, VtT, Enc);

    // 5) output projection (fp32 out): proven m97-style 128^2 GEMM (512 blocks)
    gemm128_kernel<1><<<dim3(CC / 128, BT / 128), 256, 0, stream>>>(Enc, woT, out, nullptr, BT, CC, CC);
}